// Round 6
// baseline (238.424 us; speedup 1.0000x reference)
//
#include <hip/hip_runtime.h>
#include <hip/hip_bf16.h>

typedef __hip_bfloat16 bf16_t;
using f32x4  = __attribute__((ext_vector_type(4))) float;
using bf16x8 = __attribute__((ext_vector_type(8))) short;

#define NB 4
#define NC 64
#define NC2 32
#define NH 60
#define NW 60
#define NPIX (NH*NW)         // 3600
#define HP 66                // embed padded (pad 3)
#define MP 62                // match padded (pad 1)
#define HR 20
#define RP 22                // ref padded (pad 1)
#define NL 400
#define OHW 180
#define KPAD 512

// workspace layout (floats)
#define SZ_E   (NB*HP*HP*NC)        // 1,115,136  E_t [b][row][col][c]
#define SZ_XP  (NB*NC2*MP*MP)       // 492,032    [b][c][62][62]
#define SZ_RP  (NB*NC2*RP*RP)       // 61,952     [b][c][22][22]
#define SZ_IN  (NB*NL)              // 1,600
#define SZ_Y   (NB*NPIX*NL)         // 5,760,000  y_t [b][h][w][l]
// then bf16: ApSwz 7,372,800 ; EbSwz 1,179,648 ; XpSwz 4,147,200 ; RfSwz 460,800

// embed conv1x1 + prelu -> padded, channel-fastest layout
__global__ __launch_bounds__(256) void k_conv_embed(
    const float* __restrict__ x, const float* __restrict__ Wa,
    const float* __restrict__ ba, const float* __restrict__ aa,
    float* __restrict__ E_t) {
  __shared__ float Ws[64*64];
  __shared__ float bs[64];
  __shared__ float al;
  int t = threadIdx.x;
  for (int i = t; i < 64*64; i += 256) {
    int co = i >> 6, c = i & 63;
    Ws[c*64 + co] = Wa[i];
  }
  if (t < 64) bs[t] = ba[t];
  if (t == 0) al = aa[0];
  __syncthreads();
  int lane = t & 63, wid = t >> 6;
  int pix = blockIdx.x * 4 + wid;
  int b = blockIdx.y;
  int ph = pix / NW, pw = pix % NW;
  const float* xb = x + b*NC*NPIX + pix;
  float acc = bs[lane];
  #pragma unroll 8
  for (int c = 0; c < 64; ++c)
    acc = fmaf(xb[c*NPIX], Ws[c*64 + lane], acc);
  acc = acc >= 0.f ? acc : al*acc;
  E_t[((b*HP + ph+3)*HP + (pw+3))*NC + lane] = acc;
}

// match conv1x1 + prelu -> padded [b][c2][62][62]
__global__ __launch_bounds__(256) void k_conv_match(
    const float* __restrict__ x, const float* __restrict__ Wm,
    const float* __restrict__ bm, const float* __restrict__ am,
    float* __restrict__ xp) {
  int idx = blockIdx.x*256 + threadIdx.x;
  if (idx >= NB*NC2*NPIX) return;
  int pix = idx % NPIX; int tmp = idx / NPIX;
  int co = tmp % NC2; int b = tmp / NC2;
  float alpha = am[0];
  const float* xb = x + b*NC*NPIX + pix;
  const float* wr = Wm + co*64;
  float acc = bm[co];
  #pragma unroll 8
  for (int c = 0; c < 64; ++c)
    acc = fmaf(xb[c*NPIX], wr[c], acc);
  acc = acc >= 0.f ? acc : alpha*acc;
  int ph = pix / NW, pw = pix % NW;
  xp[((b*NC2 + co)*MP + ph+1)*MP + (pw+1)] = acc;
}

// bilinear down (exact subsample at 3h+1) + conv1x1 + prelu -> padded [b][c2][22][22]
__global__ __launch_bounds__(256) void k_conv_ref(
    const float* __restrict__ x, const float* __restrict__ Wm,
    const float* __restrict__ bm, const float* __restrict__ am,
    float* __restrict__ refp) {
  int idx = blockIdx.x*256 + threadIdx.x;
  if (idx >= NB*NC2*HR*HR) return;
  int pos = idx % (HR*HR); int tmp = idx / (HR*HR);
  int co = tmp % NC2; int b = tmp / NC2;
  int hr = pos / HR, wr_ = pos % HR;
  float alpha = am[0];
  const float* xb = x + b*NC*NPIX + (3*hr+1)*NW + (3*wr_+1);
  const float* wrow = Wm + co*64;
  float acc = bm[co];
  #pragma unroll 8
  for (int c = 0; c < 64; ++c)
    acc = fmaf(xb[c*NPIX], wrow[c], acc);
  acc = acc >= 0.f ? acc : alpha*acc;
  refp[((b*NC2 + co)*RP + hr+1)*RP + (wr_+1)] = acc;
}

// per-(b,l) patch inverse norm
__global__ __launch_bounds__(64) void k_invn(
    const float* __restrict__ refp, float* __restrict__ invn) {
  int bl = blockIdx.x;
  int b = bl / NL, l = bl % NL;
  int lh = l / HR, lw = l % HR;
  int t = threadIdx.x;
  float ss = 0.f;
  for (int e = t; e < NC2*9; e += 64) {
    int c = e / 9, r = e % 9;
    int i = r / 3, j = r % 3;
    float v = refp[((b*NC2 + c)*RP + lh+i)*RP + (lw+j)];
    ss = fmaf(v, v, ss);
  }
  #pragma unroll
  for (int off = 32; off > 0; off >>= 1)
    ss += __shfl_xor(ss, off);
  if (t == 0) invn[bl] = 1.f / fmaxf(sqrtf(ss), 1e-4f);
}

// im2col(xp) -> A-fragment-swizzled bf16: [b][mblk(225)][ks(9)][slot(64)][8]
__global__ __launch_bounds__(256) void k_xpswz(
    const float* __restrict__ xp, bf16_t* __restrict__ Xp) {
  int tid = blockIdx.x*256 + threadIdx.x;   // 518,400 total
  int slot = tid & 63; int rest = tid >> 6;
  int ks = rest % 9; int rest2 = rest / 9;
  int mblk = rest2 % 225; int b = rest2 / 225;
  int m = mblk*16 + (slot & 15);
  int h = m / NW, w = m % NW;
  int k0 = ks*32 + (slot >> 4)*8;
  const float* xb = xp + (size_t)b*NC2*MP*MP;
  union { bf16_t a[8]; bf16x8 v; } u;
  #pragma unroll
  for (int j = 0; j < 8; ++j) {
    int k = k0 + j;
    int c = k / 9, r = k % 9;
    int i = r / 3, j2 = r % 3;
    u.a[j] = __float2bfloat16(xb[(c*MP + h + i)*MP + w + j2]);
  }
  *(bf16x8*)(Xp + (size_t)tid*8) = u.v;
}

// ref patches (pre-scaled by 10*invn) -> B-fragment-swizzled bf16: [b][nblk(25)][ks(9)][slot(64)][8]
__global__ __launch_bounds__(256) void k_rfswz(
    const float* __restrict__ refp, const float* __restrict__ invn,
    bf16_t* __restrict__ Rf) {
  int tid = blockIdx.x*256 + threadIdx.x;   // 57,600 total
  int slot = tid & 63; int rest = tid >> 6;
  int ks = rest % 9; int rest2 = rest / 9;
  int nblk = rest2 % 25; int b = rest2 / 25;
  int l = nblk*16 + (slot & 15);
  int lh = l / HR, lw = l % HR;
  float sc = 10.f * invn[b*NL + l];
  int k0 = ks*32 + (slot >> 4)*8;
  const float* rb = refp + (size_t)b*NC2*RP*RP;
  union { bf16_t a[8]; bf16x8 v; } u;
  #pragma unroll
  for (int j = 0; j < 8; ++j) {
    int k = k0 + j;
    int c = k / 9, r = k % 9;
    int i = r / 3, j2 = r % 3;
    u.a[j] = __float2bfloat16(rb[(c*RP + lh + i)*RP + lw + j2] * sc);
  }
  *(bf16x8*)(Rf + (size_t)tid*8) = u.v;
}

// fused correlation GEMM + softmax: one wave computes a 16(m) x 400(l) logit
// tile (25 MFMA frags), softmaxes over l in-register, stores probabilities.
// C layout: row = quad*4+r (m), col = lane&15 (l within 16-block).
// Cross-lane reduce over the quad's 16 lanes = shfl_xor 1,2,4,8.
__global__ __launch_bounds__(64) void k_csoft(
    const bf16x8* __restrict__ Xp, const bf16x8* __restrict__ Rf,
    float* __restrict__ y_t) {
  int L = threadIdx.x;
  int mt = blockIdx.x, b = blockIdx.y;     // mt in [0,225)
  const bf16x8* pa = Xp + ((size_t)(b*225 + mt)*9)*64 + L;   // +ks*64
  const bf16x8* pb = Rf + ((size_t)(b*25))*9*64 + L;         // +nf*576 +ks*64
  f32x4 acc[25];
  #pragma unroll
  for (int j = 0; j < 25; ++j) acc[j] = {0.f, 0.f, 0.f, 0.f};
  for (int ks = 0; ks < 9; ++ks) {
    bf16x8 af = pa[ks*64];
    #pragma unroll
    for (int j = 0; j < 25; ++j)
      acc[j] = __builtin_amdgcn_mfma_f32_16x16x32_bf16(af, pb[j*576 + ks*64], acc[j], 0, 0, 0);
  }
  // softmax over l per row r
  float mx[4] = {-1e30f, -1e30f, -1e30f, -1e30f};
  #pragma unroll
  for (int j = 0; j < 25; ++j)
    #pragma unroll
    for (int r = 0; r < 4; ++r) mx[r] = fmaxf(mx[r], acc[j][r]);
  #pragma unroll
  for (int off = 8; off > 0; off >>= 1)
    #pragma unroll
    for (int r = 0; r < 4; ++r) mx[r] = fmaxf(mx[r], __shfl_xor(mx[r], off));
  float sm[4] = {0.f, 0.f, 0.f, 0.f};
  #pragma unroll
  for (int j = 0; j < 25; ++j)
    #pragma unroll
    for (int r = 0; r < 4; ++r) {
      float e = expf(acc[j][r] - mx[r]);
      acc[j][r] = e;
      sm[r] += e;
    }
  #pragma unroll
  for (int off = 8; off > 0; off >>= 1)
    #pragma unroll
    for (int r = 0; r < 4; ++r) sm[r] += __shfl_xor(sm[r], off);
  float ri[4];
  #pragma unroll
  for (int r = 0; r < 4; ++r) ri[r] = 1.f / sm[r];
  int quad = L >> 4, col = L & 15;
  #pragma unroll
  for (int r = 0; r < 4; ++r) {
    int m = mt*16 + quad*4 + r;
    float* row = y_t + ((size_t)(b*NPIX + m))*NL + col;
    #pragma unroll
    for (int j = 0; j < 25; ++j)
      row[j*16] = acc[j][r] * ri[r];
  }
}

// A'[b][m=(h0,w0)][k=(u,v)] = sum_{dh,dw} y[b,(u-dh,v-dw),h0+1-dh,w0+1-dw]
// 2x4 position tile/block; zero-padded bf16 LDS window [24 slots][24x24];
// 9-term sum = 9 ds_read_u16 at constant offsets (no bounds checks).
__global__ __launch_bounds__(256) void k_aprime(
    const float* __restrict__ y_t, bf16_t* __restrict__ Ap) {
  __shared__ uint4 raw[1728];                 // 27648 B
  unsigned short* ysp = (unsigned short*)raw;
  int t = threadIdx.x;
  int b = blockIdx.z;
  int h0base = blockIdx.y*2, w0base = blockIdx.x*4;   // grid (15,30,NB)
  for (int i = t; i < 1728; i += 256) raw[i] = uint4{0,0,0,0};
  __syncthreads();
  for (int idx = t; idx < 4800; idx += 256) {
    int pos = idx / 200, l2 = idx % 200;
    int i = pos / 6, jj = pos % 6;
    int hh = h0base - 1 + i, ww = w0base - 1 + jj;
    if ((unsigned)hh < NH && (unsigned)ww < NW) {
      const float* src = y_t + ((size_t)(b*NPIX + hh*NW + ww))*NL + 2*l2;
      float v0 = src[0], v1 = src[1];
      int l = 2*l2, lh = l / HR, lw = l % HR;
      union { bf16_t h[2]; unsigned int u; } pk;
      pk.h[0] = __float2bfloat16(v0);
      pk.h[1] = __float2bfloat16(v1);
      *(unsigned int*)&ysp[pos*576 + (lh+2)*24 + (lw+2)] = pk.u;
    }
  }
  __syncthreads();
  int row = t >> 5;                 // 0..7
  int klane = t & 31;
  int h0r = row >> 2, w0r = row & 3;
  int m = (h0base + h0r)*NW + (w0base + w0r);
  int pblk = m / 80, pf = (m % 80) >> 4, mrow = m & 15;
  size_t rowbase = ((size_t)(b*45 + pblk)*16);
  const unsigned short* basep = ysp + (h0r*6 + w0r)*576;
  for (int kk = 0; kk < 16; ++kk) {
    int k = kk*32 + klane;
    float acc = 0.f;
    if (k < 484) {
      int u = k / 22, v = k - 22*u;
      const unsigned short* q = basep + u*24 + v;
      #pragma unroll
      for (int dh = 0; dh < 3; ++dh) {
        #pragma unroll
        for (int dw = 0; dw < 3; ++dw) {
          unsigned short rbits = q[dh*3480 + dw*577];
          acc += __uint_as_float(((unsigned int)rbits) << 16);
        }
      }
    }
    size_t idx = (((rowbase + (k>>5))*5 + pf)*64 + ((k>>3)&3)*16 + mrow)*8 + (k&7);
    Ap[idx] = __float2bfloat16(acc);
  }
}

// Eb[b][n=(c,rr,s)][k=(u,v)] = E_pad[b][c][3u+rr][3v+s], A-frag swizzled
__global__ __launch_bounds__(256) void k_ebswz(
    const float* __restrict__ E_t, bf16_t* __restrict__ Eb) {
  int n = blockIdx.x, b = blockIdx.y;
  int c = n / 9, n9 = n % 9, rr = n9 / 3, s = n9 % 3;
  size_t nbase = ((size_t)(b*12 + n/48)*16);
  for (int k = threadIdx.x; k < KPAD; k += 256) {
    float v = 0.f;
    if (k < 484) {
      int u = k / 22, vv = k % 22;
      v = E_t[((size_t)((b*HP + 3*u + rr)*HP + 3*vv + s))*NC + c];
    }
    size_t idx = (((nbase + (k>>5))*3 + (n%48)/16)*64 + ((k>>3)&3)*16 + (n&15))*8 + (k&7);
    Eb[idx] = __float2bfloat16(v);
  }
}

// out GEMM: out[(c,rr,s)][(h0,w0)] = (1/6) sum_k Eb[n][k] * A'[m][k]
__global__ __launch_bounds__(64) void k_tgemm(
    const bf16x8* __restrict__ Eb, const bf16x8* __restrict__ Ap,
    float* __restrict__ out) {
  int L = threadIdx.x;
  int pb = blockIdx.x, rb = blockIdx.y, b = blockIdx.z;
  const bf16x8* pa = Eb + ((size_t)(b*12 + rb)*16)*3*64 + L;
  const bf16x8* pp = Ap + ((size_t)(b*45 + pb)*16)*5*64 + L;
  f32x4 acc[3][5];
  #pragma unroll
  for (int i = 0; i < 3; ++i)
    #pragma unroll
    for (int j = 0; j < 5; ++j)
      acc[i][j] = {0.f, 0.f, 0.f, 0.f};
  bf16x8 af[3], bf[5], afn[3], bfn[5];
  #pragma unroll
  for (int i = 0; i < 3; ++i) af[i] = pa[i*64];
  #pragma unroll
  for (int j = 0; j < 5; ++j) bf[j] = pp[j*64];
  for (int ks = 0; ks < 16; ++ks) {
    if (ks < 15) {
      const bf16x8* na = pa + (ks+1)*192;
      const bf16x8* nb = pp + (ks+1)*320;
      #pragma unroll
      for (int i = 0; i < 3; ++i) afn[i] = na[i*64];
      #pragma unroll
      for (int j = 0; j < 5; ++j) bfn[j] = nb[j*64];
    }
    #pragma unroll
    for (int i = 0; i < 3; ++i)
      #pragma unroll
      for (int j = 0; j < 5; ++j)
        acc[i][j] = __builtin_amdgcn_mfma_f32_16x16x32_bf16(af[i], bf[j], acc[i][j], 0, 0, 0);
    #pragma unroll
    for (int i = 0; i < 3; ++i) af[i] = afn[i];
    #pragma unroll
    for (int j = 0; j < 5; ++j) bf[j] = bfn[j];
  }
  int quad = L >> 4, col = L & 15;
  const float sc = 1.f/6.f;
  #pragma unroll
  for (int pf = 0; pf < 5; ++pf) {
    int m = pb*80 + pf*16 + col;
    int h0 = m / 60, w0 = m % 60;
    int posoff = b*(NC*OHW*OHW) + h0*540 + w0*3;
    #pragma unroll
    for (int rf = 0; rf < 3; ++rf) {
      #pragma unroll
      for (int r = 0; r < 4; ++r) {
        int n = rb*48 + rf*16 + quad*4 + r;
        int c = n / 9, n9 = n % 9;
        int rr = n9 / 3, s = n9 % 3;
        out[posoff + c*32400 + rr*180 + s] = acc[rf][pf][r] * sc;
      }
    }
  }
}

extern "C" void kernel_launch(void* const* d_in, const int* in_sizes, int n_in,
                              void* d_out, int out_size, void* d_ws, size_t ws_size,
                              hipStream_t stream) {
  (void)in_sizes; (void)n_in; (void)out_size; (void)ws_size;
  const float* x   = (const float*)d_in[0];
  const float* Wa  = (const float*)d_in[1];
  const float* ba  = (const float*)d_in[2];
  const float* aa  = (const float*)d_in[3];
  const float* Wm1 = (const float*)d_in[4];
  const float* bm1 = (const float*)d_in[5];
  const float* am1 = (const float*)d_in[6];
  const float* Wm2 = (const float*)d_in[7];
  const float* bm2 = (const float*)d_in[8];
  const float* am2 = (const float*)d_in[9];
  float* out = (float*)d_out;

  float* E_t  = (float*)d_ws;
  float* xp   = E_t + SZ_E;
  float* refp = xp + SZ_XP;
  float* invn = refp + SZ_RP;
  float* y_t  = invn + SZ_IN;
  bf16_t* ApSwz = (bf16_t*)(y_t + SZ_Y);                 // 7,372,800 bf16
  bf16_t* EbSwz = ApSwz + (size_t)NB*45*16*5*64*8;       // 1,179,648 bf16
  bf16_t* XpSwz = EbSwz + (size_t)NB*12*16*3*64*8;       // 4,147,200 bf16
  bf16_t* RfSwz = XpSwz + (size_t)NB*225*9*64*8;         //   460,800 bf16

  hipMemsetAsync(d_ws, 0, (size_t)(SZ_E + SZ_XP + SZ_RP)*sizeof(float), stream);

  k_conv_embed<<<dim3(900, NB), 256, 0, stream>>>(x, Wa, ba, aa, E_t);
  k_conv_match<<<(NB*NC2*NPIX)/256, 256, 0, stream>>>(x, Wm1, bm1, am1, xp);
  k_conv_ref<<<(NB*NC2*HR*HR)/256, 256, 0, stream>>>(x, Wm2, bm2, am2, refp);
  k_invn<<<NB*NL, 64, 0, stream>>>(refp, invn);
  k_xpswz<<<2025, 256, 0, stream>>>(xp, XpSwz);
  k_rfswz<<<225, 256, 0, stream>>>(refp, invn, RfSwz);
  k_csoft<<<dim3(225, NB), 64, 0, stream>>>((const bf16x8*)XpSwz, (const bf16x8*)RfSwz, y_t);
  k_ebswz<<<dim3(576, NB), 256, 0, stream>>>(E_t, EbSwz);
  k_aprime<<<dim3(15, 30, NB), 256, 0, stream>>>(y_t, ApSwz);
  k_tgemm<<<dim3(45, 12, NB), 64, 0, stream>>>((const bf16x8*)EbSwz, (const bf16x8*)ApSwz, out);
}

// Round 7
// 212.266 us; speedup vs baseline: 1.1232x; 1.1232x over previous
//
#include <hip/hip_runtime.h>
#include <hip/hip_bf16.h>

typedef __hip_bfloat16 bf16_t;
using f32x4  = __attribute__((ext_vector_type(4))) float;
using bf16x8 = __attribute__((ext_vector_type(8))) short;

#define NB 4
#define NC 64
#define NC2 32
#define NH 60
#define NW 60
#define NPIX (NH*NW)         // 3600
#define HP 66                // embed padded (pad 3)
#define MP 62                // match padded (pad 1)
#define HR 20
#define RP 22                // ref padded (pad 1)
#define NL 400
#define OHW 180
#define KPAD 512

// workspace layout (floats)
#define SZ_E   (NB*HP*HP*NC)        // 1,115,136  E_t [b][row][col][c]
#define SZ_XP  (NB*NC2*MP*MP)       // 492,032    [b][c][62][62]
#define SZ_RP  (NB*NC2*RP*RP)       // 61,952     [b][c][22][22]
#define SZ_IN  (NB*NL)              // 1,600
#define SZ_Y   (NB*NPIX*NL)         // 5,760,000  y_t [b][h][w][l] fp32 logits
// then bf16: ApSwz 7,372,800 ; EbSwz 1,179,648 ; XpSwz 4,147,200 ; RfSwz 460,800 ;
//            y_b 5,760,000 (bf16 probs)

// embed conv1x1 + prelu -> padded, channel-fastest layout
__global__ __launch_bounds__(256) void k_conv_embed(
    const float* __restrict__ x, const float* __restrict__ Wa,
    const float* __restrict__ ba, const float* __restrict__ aa,
    float* __restrict__ E_t) {
  __shared__ float Ws[64*64];
  __shared__ float bs[64];
  __shared__ float al;
  int t = threadIdx.x;
  for (int i = t; i < 64*64; i += 256) {
    int co = i >> 6, c = i & 63;
    Ws[c*64 + co] = Wa[i];
  }
  if (t < 64) bs[t] = ba[t];
  if (t == 0) al = aa[0];
  __syncthreads();
  int lane = t & 63, wid = t >> 6;
  int pix = blockIdx.x * 4 + wid;
  int b = blockIdx.y;
  int ph = pix / NW, pw = pix % NW;
  const float* xb = x + b*NC*NPIX + pix;
  float acc = bs[lane];
  #pragma unroll 8
  for (int c = 0; c < 64; ++c)
    acc = fmaf(xb[c*NPIX], Ws[c*64 + lane], acc);
  acc = acc >= 0.f ? acc : al*acc;
  E_t[((b*HP + ph+3)*HP + (pw+3))*NC + lane] = acc;
}

// merged: match conv1x1 (blocks 0..1799) + ref conv1x1 (blocks 1800..1999)
__global__ __launch_bounds__(256) void k_conv_mr(
    const float* __restrict__ x,
    const float* __restrict__ Wm1, const float* __restrict__ bm1, const float* __restrict__ am1,
    const float* __restrict__ Wm2, const float* __restrict__ bm2, const float* __restrict__ am2,
    float* __restrict__ xp, float* __restrict__ refp) {
  int bid = blockIdx.x;
  if (bid < 1800) {
    int idx = bid*256 + threadIdx.x;
    int pix = idx % NPIX; int tmp = idx / NPIX;
    int co = tmp % NC2; int b = tmp / NC2;
    float alpha = am1[0];
    const float* xb = x + b*NC*NPIX + pix;
    const float* wr = Wm1 + co*64;
    float acc = bm1[co];
    #pragma unroll 8
    for (int c = 0; c < 64; ++c)
      acc = fmaf(xb[c*NPIX], wr[c], acc);
    acc = acc >= 0.f ? acc : alpha*acc;
    int ph = pix / NW, pw = pix % NW;
    xp[((b*NC2 + co)*MP + ph+1)*MP + (pw+1)] = acc;
  } else {
    int idx = (bid - 1800)*256 + threadIdx.x;
    int pos = idx % (HR*HR); int tmp = idx / (HR*HR);
    int co = tmp % NC2; int b = tmp / NC2;
    int hr = pos / HR, wr_ = pos % HR;
    float alpha = am2[0];
    const float* xb = x + b*NC*NPIX + (3*hr+1)*NW + (3*wr_+1);
    const float* wrow = Wm2 + co*64;
    float acc = bm2[co];
    #pragma unroll 8
    for (int c = 0; c < 64; ++c)
      acc = fmaf(xb[c*NPIX], wrow[c], acc);
    acc = acc >= 0.f ? acc : alpha*acc;
    refp[((b*NC2 + co)*RP + hr+1)*RP + (wr_+1)] = acc;
  }
}

// per-(b,l) patch inverse norm
__global__ __launch_bounds__(64) void k_invn(
    const float* __restrict__ refp, float* __restrict__ invn) {
  int bl = blockIdx.x;
  int b = bl / NL, l = bl % NL;
  int lh = l / HR, lw = l % HR;
  int t = threadIdx.x;
  float ss = 0.f;
  for (int e = t; e < NC2*9; e += 64) {
    int c = e / 9, r = e % 9;
    int i = r / 3, j = r % 3;
    float v = refp[((b*NC2 + c)*RP + lh+i)*RP + (lw+j)];
    ss = fmaf(v, v, ss);
  }
  #pragma unroll
  for (int off = 32; off > 0; off >>= 1)
    ss += __shfl_xor(ss, off);
  if (t == 0) invn[bl] = 1.f / fmaxf(sqrtf(ss), 1e-4f);
}

// merged swizzles: [0,2025) xp-im2col ; [2025,2250) ref patches ; [2250,4554) Eb
__global__ __launch_bounds__(256) void k_swz(
    const float* __restrict__ xp, const float* __restrict__ refp,
    const float* __restrict__ invn, const float* __restrict__ E_t,
    bf16_t* __restrict__ Xp, bf16_t* __restrict__ Rf, bf16_t* __restrict__ Eb) {
  int bid = blockIdx.x;
  if (bid < 2025) {
    int tid = bid*256 + threadIdx.x;   // 518,400 total
    int slot = tid & 63; int rest = tid >> 6;
    int ks = rest % 9; int rest2 = rest / 9;
    int mblk = rest2 % 225; int b = rest2 / 225;
    int m = mblk*16 + (slot & 15);
    int h = m / NW, w = m % NW;
    int k0 = ks*32 + (slot >> 4)*8;
    const float* xb = xp + (size_t)b*NC2*MP*MP;
    union { bf16_t a[8]; bf16x8 v; } u;
    #pragma unroll
    for (int j = 0; j < 8; ++j) {
      int k = k0 + j;
      int c = k / 9, r = k % 9;
      int i = r / 3, j2 = r % 3;
      u.a[j] = __float2bfloat16(xb[(c*MP + h + i)*MP + w + j2]);
    }
    *(bf16x8*)(Xp + (size_t)tid*8) = u.v;
  } else if (bid < 2250) {
    int tid = (bid - 2025)*256 + threadIdx.x;   // 57,600 total
    int slot = tid & 63; int rest = tid >> 6;
    int ks = rest % 9; int rest2 = rest / 9;
    int nblk = rest2 % 25; int b = rest2 / 25;
    int l = nblk*16 + (slot & 15);
    int lh = l / HR, lw = l % HR;
    float sc = 10.f * invn[b*NL + l];
    int k0 = ks*32 + (slot >> 4)*8;
    const float* rb = refp + (size_t)b*NC2*RP*RP;
    union { bf16_t a[8]; bf16x8 v; } u;
    #pragma unroll
    for (int j = 0; j < 8; ++j) {
      int k = k0 + j;
      int c = k / 9, r = k % 9;
      int i = r / 3, j2 = r % 3;
      u.a[j] = __float2bfloat16(rb[(c*RP + lh + i)*RP + lw + j2] * sc);
    }
    *(bf16x8*)(Rf + (size_t)tid*8) = u.v;
  } else {
    int r2 = bid - 2250;          // 2304 blocks
    int n = r2 % 576, b = r2 / 576;
    int c = n / 9, n9 = n % 9, rr = n9 / 3, s = n9 % 3;
    size_t nbase = ((size_t)(b*12 + n/48)*16);
    for (int k = threadIdx.x; k < KPAD; k += 256) {
      float v = 0.f;
      if (k < 484) {
        int u = k / 22, vv = k % 22;
        v = E_t[((size_t)((b*HP + 3*u + rr)*HP + 3*vv + s))*NC + c];
      }
      size_t idx = (((nbase + (k>>5))*3 + (n%48)/16)*64 + ((k>>3)&3)*16 + (n&15))*8 + (k&7);
      Eb[idx] = __float2bfloat16(v);
    }
  }
}

// correlation GEMM: y_t[b][m][l] = sum_k Xp[m][k]*Rf[l][k]  (fp32 logits)
__global__ __launch_bounds__(64) void k_cgemm(
    const bf16x8* __restrict__ Xp, const bf16x8* __restrict__ Rf,
    float* __restrict__ y_t) {
  int L = threadIdx.x;
  int nt = blockIdx.x, mt = blockIdx.y, b = blockIdx.z;
  const bf16x8* pa = Xp + ((size_t)(b*225 + mt*3)*9)*64 + L;
  const bf16x8* pb = Rf + ((size_t)(b*25 + nt*5)*9)*64 + L;
  f32x4 acc[3][5];
  #pragma unroll
  for (int i = 0; i < 3; ++i)
    #pragma unroll
    for (int j = 0; j < 5; ++j)
      acc[i][j] = {0.f, 0.f, 0.f, 0.f};
  bf16x8 af[3], bf[5], afn[3], bfn[5];
  #pragma unroll
  for (int i = 0; i < 3; ++i) af[i] = pa[i*576];
  #pragma unroll
  for (int j = 0; j < 5; ++j) bf[j] = pb[j*576];
  for (int ks = 0; ks < 9; ++ks) {
    if (ks < 8) {
      #pragma unroll
      for (int i = 0; i < 3; ++i) afn[i] = pa[i*576 + (ks+1)*64];
      #pragma unroll
      for (int j = 0; j < 5; ++j) bfn[j] = pb[j*576 + (ks+1)*64];
    }
    #pragma unroll
    for (int i = 0; i < 3; ++i)
      #pragma unroll
      for (int j = 0; j < 5; ++j)
        acc[i][j] = __builtin_amdgcn_mfma_f32_16x16x32_bf16(af[i], bf[j], acc[i][j], 0, 0, 0);
    #pragma unroll
    for (int i = 0; i < 3; ++i) af[i] = afn[i];
    #pragma unroll
    for (int j = 0; j < 5; ++j) bf[j] = bfn[j];
  }
  int quad = L >> 4, col = L & 15;
  #pragma unroll
  for (int mf = 0; mf < 3; ++mf) {
    #pragma unroll
    for (int r = 0; r < 4; ++r) {
      int m = mt*48 + mf*16 + quad*4 + r;
      float* row = y_t + ((size_t)(b*NPIX + m))*NL + nt*80 + col;
      #pragma unroll
      for (int nf = 0; nf < 5; ++nf)
        row[nf*16] = acc[mf][nf][r];
    }
  }
}

// softmax over L per (b,h,w); reads fp32 logits, writes packed-bf16 probs.
// One wave per position; lane owns pairs (2*l2, 2*l2+1), l2 = lane + 64k.
__global__ __launch_bounds__(256) void k_softmax(
    const float* __restrict__ y_t, unsigned int* __restrict__ y_b32) {
  int t = threadIdx.x;
  int lane = t & 63, wid = t >> 6;
  int gpos = blockIdx.x*4 + wid;
  int b = gpos / NPIX, rem = gpos % NPIX;
  const float* yp = y_t + ((size_t)(b*NPIX + rem))*NL;
  unsigned int* ob = y_b32 + ((size_t)(b*NPIX + rem))*(NL/2);
  float2 vals[4];
  float m = -1e30f;
  #pragma unroll
  for (int k = 0; k < 4; ++k) {
    int l2 = lane + 64*k;
    float2 v = {-1e30f, -1e30f};
    if (l2 < 200) v = *(const float2*)(yp + 2*l2);
    vals[k] = v;
    m = fmaxf(m, fmaxf(v.x, v.y));
  }
  #pragma unroll
  for (int off = 32; off > 0; off >>= 1)
    m = fmaxf(m, __shfl_xor(m, off));
  float s = 0.f;
  #pragma unroll
  for (int k = 0; k < 4; ++k) {
    float ex = expf(vals[k].x - m);
    float ey = expf(vals[k].y - m);
    vals[k].x = ex; vals[k].y = ey;
    s += ex + ey;
  }
  #pragma unroll
  for (int off = 32; off > 0; off >>= 1)
    s += __shfl_xor(s, off);
  float r = 1.f / s;
  #pragma unroll
  for (int k = 0; k < 4; ++k) {
    int l2 = lane + 64*k;
    if (l2 < 200) {
      union { bf16_t h[2]; unsigned int u; } pk;
      pk.h[0] = __float2bfloat16(vals[k].x * r);
      pk.h[1] = __float2bfloat16(vals[k].y * r);
      ob[l2] = pk.u;
    }
  }
}

// A'[b][m=(h0,w0)][k=(u,v)] = sum_{dh,dw} p[b,(u-dh,v-dw),h0+1-dh,w0+1-dw]
// stages bf16 probs (u32 pair copies) into zero-padded LDS window.
__global__ __launch_bounds__(256) void k_aprime(
    const unsigned int* __restrict__ y_b32, bf16_t* __restrict__ Ap) {
  __shared__ uint4 raw[1728];                 // 27648 B
  unsigned short* ysp = (unsigned short*)raw;
  int t = threadIdx.x;
  int b = blockIdx.z;
  int h0base = blockIdx.y*2, w0base = blockIdx.x*4;   // grid (15,30,NB)
  for (int i = t; i < 1728; i += 256) raw[i] = uint4{0,0,0,0};
  __syncthreads();
  for (int idx = t; idx < 4800; idx += 256) {
    int pos = idx / 200, l2 = idx % 200;
    int i = pos / 6, jj = pos % 6;
    int hh = h0base - 1 + i, ww = w0base - 1 + jj;
    if ((unsigned)hh < NH && (unsigned)ww < NW) {
      unsigned int pk = y_b32[((size_t)(b*NPIX + hh*NW + ww))*200 + l2];
      int l = 2*l2, lh = l / HR, lw = l % HR;
      *(unsigned int*)&ysp[pos*576 + (lh+2)*24 + (lw+2)] = pk;
    }
  }
  __syncthreads();
  int row = t >> 5;                 // 0..7
  int klane = t & 31;
  int h0r = row >> 2, w0r = row & 3;
  int m = (h0base + h0r)*NW + (w0base + w0r);
  int pblk = m / 80, pf = (m % 80) >> 4, mrow = m & 15;
  size_t rowbase = ((size_t)(b*45 + pblk)*16);
  const unsigned short* basep = ysp + (h0r*6 + w0r)*576;
  for (int kk = 0; kk < 16; ++kk) {
    int k = kk*32 + klane;
    float acc = 0.f;
    if (k < 484) {
      int u = k / 22, v = k - 22*u;
      const unsigned short* q = basep + u*24 + v;
      #pragma unroll
      for (int dh = 0; dh < 3; ++dh) {
        #pragma unroll
        for (int dw = 0; dw < 3; ++dw) {
          unsigned short rbits = q[dh*3480 + dw*577];
          acc += __uint_as_float(((unsigned int)rbits) << 16);
        }
      }
    }
    size_t idx = (((rowbase + (k>>5))*5 + pf)*64 + ((k>>3)&3)*16 + mrow)*8 + (k&7);
    Ap[idx] = __float2bfloat16(acc);
  }
}

// out GEMM: out[(c,rr,s)][(h0,w0)] = (1/6) sum_k Eb[n][k] * A'[m][k]
__global__ __launch_bounds__(64) void k_tgemm(
    const bf16x8* __restrict__ Eb, const bf16x8* __restrict__ Ap,
    float* __restrict__ out) {
  int L = threadIdx.x;
  int pb = blockIdx.x, rb = blockIdx.y, b = blockIdx.z;
  const bf16x8* pa = Eb + ((size_t)(b*12 + rb)*16)*3*64 + L;
  const bf16x8* pp = Ap + ((size_t)(b*45 + pb)*16)*5*64 + L;
  f32x4 acc[3][5];
  #pragma unroll
  for (int i = 0; i < 3; ++i)
    #pragma unroll
    for (int j = 0; j < 5; ++j)
      acc[i][j] = {0.f, 0.f, 0.f, 0.f};
  bf16x8 af[3], bf[5], afn[3], bfn[5];
  #pragma unroll
  for (int i = 0; i < 3; ++i) af[i] = pa[i*64];
  #pragma unroll
  for (int j = 0; j < 5; ++j) bf[j] = pp[j*64];
  for (int ks = 0; ks < 16; ++ks) {
    if (ks < 15) {
      const bf16x8* na = pa + (ks+1)*192;
      const bf16x8* nb = pp + (ks+1)*320;
      #pragma unroll
      for (int i = 0; i < 3; ++i) afn[i] = na[i*64];
      #pragma unroll
      for (int j = 0; j < 5; ++j) bfn[j] = nb[j*64];
    }
    #pragma unroll
    for (int i = 0; i < 3; ++i)
      #pragma unroll
      for (int j = 0; j < 5; ++j)
        acc[i][j] = __builtin_amdgcn_mfma_f32_16x16x32_bf16(af[i], bf[j], acc[i][j], 0, 0, 0);
    #pragma unroll
    for (int i = 0; i < 3; ++i) af[i] = afn[i];
    #pragma unroll
    for (int j = 0; j < 5; ++j) bf[j] = bfn[j];
  }
  int quad = L >> 4, col = L & 15;
  const float sc = 1.f/6.f;
  #pragma unroll
  for (int pf = 0; pf < 5; ++pf) {
    int m = pb*80 + pf*16 + col;
    int h0 = m / 60, w0 = m % 60;
    int posoff = b*(NC*OHW*OHW) + h0*540 + w0*3;
    #pragma unroll
    for (int rf = 0; rf < 3; ++rf) {
      #pragma unroll
      for (int r = 0; r < 4; ++r) {
        int n = rb*48 + rf*16 + quad*4 + r;
        int c = n / 9, n9 = n % 9;
        int rr = n9 / 3, s = n9 % 3;
        out[posoff + c*32400 + rr*180 + s] = acc[rf][pf][r] * sc;
      }
    }
  }
}

extern "C" void kernel_launch(void* const* d_in, const int* in_sizes, int n_in,
                              void* d_out, int out_size, void* d_ws, size_t ws_size,
                              hipStream_t stream) {
  (void)in_sizes; (void)n_in; (void)out_size; (void)ws_size;
  const float* x   = (const float*)d_in[0];
  const float* Wa  = (const float*)d_in[1];
  const float* ba  = (const float*)d_in[2];
  const float* aa  = (const float*)d_in[3];
  const float* Wm1 = (const float*)d_in[4];
  const float* bm1 = (const float*)d_in[5];
  const float* am1 = (const float*)d_in[6];
  const float* Wm2 = (const float*)d_in[7];
  const float* bm2 = (const float*)d_in[8];
  const float* am2 = (const float*)d_in[9];
  float* out = (float*)d_out;

  float* E_t  = (float*)d_ws;
  float* xp   = E_t + SZ_E;
  float* refp = xp + SZ_XP;
  float* invn = refp + SZ_RP;
  float* y_t  = invn + SZ_IN;
  bf16_t* ApSwz = (bf16_t*)(y_t + SZ_Y);                 // 7,372,800 bf16
  bf16_t* EbSwz = ApSwz + (size_t)NB*45*16*5*64*8;       // 1,179,648 bf16
  bf16_t* XpSwz = EbSwz + (size_t)NB*12*16*3*64*8;       // 4,147,200 bf16
  bf16_t* RfSwz = XpSwz + (size_t)NB*225*9*64*8;         //   460,800 bf16
  unsigned int* y_b32 = (unsigned int*)(RfSwz + 460800); // 5,760,000 bf16 probs

  hipMemsetAsync(d_ws, 0, (size_t)(SZ_E + SZ_XP + SZ_RP)*sizeof(float), stream);

  k_conv_embed<<<dim3(900, NB), 256, 0, stream>>>(x, Wa, ba, aa, E_t);
  k_conv_mr<<<2000, 256, 0, stream>>>(x, Wm1, bm1, am1, Wm2, bm2, am2, xp, refp);
  k_invn<<<NB*NL, 64, 0, stream>>>(refp, invn);
  k_swz<<<4554, 256, 0, stream>>>(xp, refp, invn, E_t, XpSwz, RfSwz, EbSwz);
  k_cgemm<<<dim3(5, 75, NB), 64, 0, stream>>>((const bf16x8*)XpSwz, (const bf16x8*)RfSwz, y_t);
  k_softmax<<<(NB*NPIX)/4, 256, 0, stream>>>(y_t, y_b32);
  k_aprime<<<dim3(15, 30, NB), 256, 0, stream>>>(y_b32, ApSwz);
  k_tgemm<<<dim3(45, 12, NB), 64, 0, stream>>>((const bf16x8*)EbSwz, (const bf16x8*)ApSwz, out);
}

// Round 8
// 201.603 us; speedup vs baseline: 1.1826x; 1.0529x over previous
//
#include <hip/hip_runtime.h>
#include <hip/hip_bf16.h>

typedef __hip_bfloat16 bf16_t;
using f32x4  = __attribute__((ext_vector_type(4))) float;
using bf16x8 = __attribute__((ext_vector_type(8))) short;

#define NB 4
#define NC 64
#define NC2 32
#define NH 60
#define NW 60
#define NPIX (NH*NW)         // 3600
#define HP 66                // embed padded (pad 3)
#define MP 62                // match padded (pad 1)
#define HR 20
#define RP 22                // ref padded (pad 1)
#define NL 400
#define OHW 180
#define KPAD 512

// workspace layout (floats)
#define SZ_E   (NB*HP*HP*NC)        // 1,115,136  E_t [b][row][col][c]
#define SZ_XP  (NB*NC2*MP*MP)       // 492,032    [b][c][62][62]
#define SZ_RP  (NB*NC2*RP*RP)       // 61,952     [b][c][22][22]
#define SZ_IN  (NB*NL)              // 1,600
#define SZ_Y   (NB*NPIX*NL)         // region sized for fp32 hist; holds bf16 logits now
// then bf16: ApSwz 7,372,800 ; EbSwz 1,179,648 ; XpSwz 4,147,200 ; RfSwz 460,800

// merged conv1x1+prelu: [0,3600) embed ; [3600,5400) match ; [5400,5600) ref
__global__ __launch_bounds__(256) void k_conv(
    const float* __restrict__ x,
    const float* __restrict__ Wa,  const float* __restrict__ ba,  const float* __restrict__ aa,
    const float* __restrict__ Wm1, const float* __restrict__ bm1, const float* __restrict__ am1,
    const float* __restrict__ Wm2, const float* __restrict__ bm2, const float* __restrict__ am2,
    float* __restrict__ E_t, float* __restrict__ xp, float* __restrict__ refp) {
  int bid = blockIdx.x;
  int t = threadIdx.x;
  if (bid < 3600) {
    __shared__ float Ws[64*64];
    __shared__ float bs[64];
    __shared__ float al;
    int b = bid / 900, pblk = bid % 900;
    for (int i = t; i < 64*64; i += 256) {
      int co = i >> 6, c = i & 63;
      Ws[c*64 + co] = Wa[i];
    }
    if (t < 64) bs[t] = ba[t];
    if (t == 0) al = aa[0];
    __syncthreads();
    int lane = t & 63, wid = t >> 6;
    int pix = pblk*4 + wid;
    int ph = pix / NW, pw = pix % NW;
    const float* xb = x + b*NC*NPIX + pix;
    float acc = bs[lane];
    #pragma unroll 8
    for (int c = 0; c < 64; ++c)
      acc = fmaf(xb[c*NPIX], Ws[c*64 + lane], acc);
    acc = acc >= 0.f ? acc : al*acc;
    E_t[((b*HP + ph+3)*HP + (pw+3))*NC + lane] = acc;
  } else if (bid < 5400) {
    int idx = (bid - 3600)*256 + t;
    int pix = idx % NPIX; int tmp = idx / NPIX;
    int co = tmp % NC2; int b = tmp / NC2;
    float alpha = am1[0];
    const float* xb = x + b*NC*NPIX + pix;
    const float* wr = Wm1 + co*64;
    float acc = bm1[co];
    #pragma unroll 8
    for (int c = 0; c < 64; ++c)
      acc = fmaf(xb[c*NPIX], wr[c], acc);
    acc = acc >= 0.f ? acc : alpha*acc;
    int ph = pix / NW, pw = pix % NW;
    xp[((b*NC2 + co)*MP + ph+1)*MP + (pw+1)] = acc;
  } else {
    int idx = (bid - 5400)*256 + t;
    int pos = idx % (HR*HR); int tmp = idx / (HR*HR);
    int co = tmp % NC2; int b = tmp / NC2;
    int hr = pos / HR, wr_ = pos % HR;
    float alpha = am2[0];
    const float* xb = x + b*NC*NPIX + (3*hr+1)*NW + (3*wr_+1);
    const float* wrow = Wm2 + co*64;
    float acc = bm2[co];
    #pragma unroll 8
    for (int c = 0; c < 64; ++c)
      acc = fmaf(xb[c*NPIX], wrow[c], acc);
    acc = acc >= 0.f ? acc : alpha*acc;
    refp[((b*NC2 + co)*RP + hr+1)*RP + (wr_+1)] = acc;
  }
}

// per-(b,l) patch inverse norm
__global__ __launch_bounds__(64) void k_invn(
    const float* __restrict__ refp, float* __restrict__ invn) {
  int bl = blockIdx.x;
  int b = bl / NL, l = bl % NL;
  int lh = l / HR, lw = l % HR;
  int t = threadIdx.x;
  float ss = 0.f;
  for (int e = t; e < NC2*9; e += 64) {
    int c = e / 9, r = e % 9;
    int i = r / 3, j = r % 3;
    float v = refp[((b*NC2 + c)*RP + lh+i)*RP + (lw+j)];
    ss = fmaf(v, v, ss);
  }
  #pragma unroll
  for (int off = 32; off > 0; off >>= 1)
    ss += __shfl_xor(ss, off);
  if (t == 0) invn[bl] = 1.f / fmaxf(sqrtf(ss), 1e-4f);
}

// merged swizzles: [0,2025) xp-im2col ; [2025,2250) ref patches ; [2250,4554) Eb
__global__ __launch_bounds__(256) void k_swz(
    const float* __restrict__ xp, const float* __restrict__ refp,
    const float* __restrict__ invn, const float* __restrict__ E_t,
    bf16_t* __restrict__ Xp, bf16_t* __restrict__ Rf, bf16_t* __restrict__ Eb) {
  int bid = blockIdx.x;
  if (bid < 2025) {
    int tid = bid*256 + threadIdx.x;   // 518,400 total
    int slot = tid & 63; int rest = tid >> 6;
    int ks = rest % 9; int rest2 = rest / 9;
    int mblk = rest2 % 225; int b = rest2 / 225;
    int m = mblk*16 + (slot & 15);
    int h = m / NW, w = m % NW;
    int k0 = ks*32 + (slot >> 4)*8;
    const float* xb = xp + (size_t)b*NC2*MP*MP;
    union { bf16_t a[8]; bf16x8 v; } u;
    #pragma unroll
    for (int j = 0; j < 8; ++j) {
      int k = k0 + j;
      int c = k / 9, r = k % 9;
      int i = r / 3, j2 = r % 3;
      u.a[j] = __float2bfloat16(xb[(c*MP + h + i)*MP + w + j2]);
    }
    *(bf16x8*)(Xp + (size_t)tid*8) = u.v;
  } else if (bid < 2250) {
    int tid = (bid - 2025)*256 + threadIdx.x;   // 57,600 total
    int slot = tid & 63; int rest = tid >> 6;
    int ks = rest % 9; int rest2 = rest / 9;
    int nblk = rest2 % 25; int b = rest2 / 25;
    int l = nblk*16 + (slot & 15);
    int lh = l / HR, lw = l % HR;
    float sc = 10.f * invn[b*NL + l];
    int k0 = ks*32 + (slot >> 4)*8;
    const float* rb = refp + (size_t)b*NC2*RP*RP;
    union { bf16_t a[8]; bf16x8 v; } u;
    #pragma unroll
    for (int j = 0; j < 8; ++j) {
      int k = k0 + j;
      int c = k / 9, r = k % 9;
      int i = r / 3, j2 = r % 3;
      u.a[j] = __float2bfloat16(rb[(c*RP + lh + i)*RP + lw + j2] * sc);
    }
    *(bf16x8*)(Rf + (size_t)tid*8) = u.v;
  } else {
    int r2 = bid - 2250;          // 2304 blocks
    int n = r2 % 576, b = r2 / 576;
    int c = n / 9, n9 = n % 9, rr = n9 / 3, s = n9 % 3;
    size_t nbase = ((size_t)(b*12 + n/48)*16);
    for (int k = threadIdx.x; k < KPAD; k += 256) {
      float v = 0.f;
      if (k < 484) {
        int u = k / 22, vv = k % 22;
        v = E_t[((size_t)((b*HP + 3*u + rr)*HP + 3*vv + s))*NC + c];
      }
      size_t idx = (((nbase + (k>>5))*3 + (n%48)/16)*64 + ((k>>3)&3)*16 + (n&15))*8 + (k&7);
      Eb[idx] = __float2bfloat16(v);
    }
  }
}

// correlation GEMM: bf16 logits y_bl[b][m][l] = bf16( sum_k Xp[m][k]*Rf[l][k] )
__global__ __launch_bounds__(64) void k_cgemm(
    const bf16x8* __restrict__ Xp, const bf16x8* __restrict__ Rf,
    bf16_t* __restrict__ y_bl) {
  int L = threadIdx.x;
  int nt = blockIdx.x, mt = blockIdx.y, b = blockIdx.z;
  const bf16x8* pa = Xp + ((size_t)(b*225 + mt*3)*9)*64 + L;
  const bf16x8* pb = Rf + ((size_t)(b*25 + nt*5)*9)*64 + L;
  f32x4 acc[3][5];
  #pragma unroll
  for (int i = 0; i < 3; ++i)
    #pragma unroll
    for (int j = 0; j < 5; ++j)
      acc[i][j] = {0.f, 0.f, 0.f, 0.f};
  bf16x8 af[3], bf[5], afn[3], bfn[5];
  #pragma unroll
  for (int i = 0; i < 3; ++i) af[i] = pa[i*576];
  #pragma unroll
  for (int j = 0; j < 5; ++j) bf[j] = pb[j*576];
  for (int ks = 0; ks < 9; ++ks) {
    if (ks < 8) {
      #pragma unroll
      for (int i = 0; i < 3; ++i) afn[i] = pa[i*576 + (ks+1)*64];
      #pragma unroll
      for (int j = 0; j < 5; ++j) bfn[j] = pb[j*576 + (ks+1)*64];
    }
    #pragma unroll
    for (int i = 0; i < 3; ++i)
      #pragma unroll
      for (int j = 0; j < 5; ++j)
        acc[i][j] = __builtin_amdgcn_mfma_f32_16x16x32_bf16(af[i], bf[j], acc[i][j], 0, 0, 0);
    #pragma unroll
    for (int i = 0; i < 3; ++i) af[i] = afn[i];
    #pragma unroll
    for (int j = 0; j < 5; ++j) bf[j] = bfn[j];
  }
  int quad = L >> 4, col = L & 15;
  #pragma unroll
  for (int mf = 0; mf < 3; ++mf) {
    #pragma unroll
    for (int r = 0; r < 4; ++r) {
      int m = mt*48 + mf*16 + quad*4 + r;
      bf16_t* row = y_bl + ((size_t)(b*NPIX + m))*NL + nt*80 + col;
      #pragma unroll
      for (int nf = 0; nf < 5; ++nf)
        row[nf*16] = __float2bfloat16(acc[mf][nf][r]);
    }
  }
}

__device__ __forceinline__ float lo_bf(unsigned int u) {
  return __uint_as_float(u << 16);
}
__device__ __forceinline__ float hi_bf(unsigned int u) {
  return __uint_as_float(u & 0xffff0000u);
}

// fused softmax + A': block = 2x4 output positions, 4x6 halo.
// Phase 1: wave w softmaxes halo row w (6 positions) from bf16 logits,
//          writes bf16 probs into zero-padded LDS window [24][24x24].
// Phase 2: A'[m][k=(u,v)] = 9-point LDS sum, swizzled bf16 store.
__global__ __launch_bounds__(256) void k_saprime(
    const unsigned int* __restrict__ y_b32, bf16_t* __restrict__ Ap) {
  __shared__ uint4 raw[1728];                 // 27648 B
  unsigned short* ysp = (unsigned short*)raw;
  int t = threadIdx.x;
  int b = blockIdx.z;
  int h0base = blockIdx.y*2, w0base = blockIdx.x*4;   // grid (15,30,NB)
  for (int i = t; i < 1728; i += 256) raw[i] = uint4{0,0,0,0};
  __syncthreads();

  int wave = t >> 6, lane = t & 63;
  bool has4 = lane < 8;
  int hh = h0base - 1 + wave;                 // halo row per wave
  bool hok = (unsigned)hh < NH;
  unsigned int vv[6][4];
  #pragma unroll
  for (int it = 0; it < 6; ++it) {
    int ww = w0base - 1 + it;
    if (hok && (unsigned)ww < NW) {
      const unsigned int* src = y_b32 + ((size_t)(b*NPIX + hh*NW + ww))*200;
      vv[it][0] = src[lane];
      vv[it][1] = src[lane+64];
      vv[it][2] = src[lane+128];
      vv[it][3] = has4 ? src[lane+192] : 0u;
    }
  }
  #pragma unroll
  for (int it = 0; it < 6; ++it) {
    int ww = w0base - 1 + it;
    if (!(hok && (unsigned)ww < NW)) continue;
    float f[8];
    #pragma unroll
    for (int k = 0; k < 3; ++k) {
      f[2*k]   = lo_bf(vv[it][k]);
      f[2*k+1] = hi_bf(vv[it][k]);
    }
    f[6] = has4 ? lo_bf(vv[it][3]) : -1e30f;
    f[7] = has4 ? hi_bf(vv[it][3]) : -1e30f;
    float m = -1e30f;
    #pragma unroll
    for (int k = 0; k < 8; ++k) m = fmaxf(m, f[k]);
    #pragma unroll
    for (int off = 32; off > 0; off >>= 1)
      m = fmaxf(m, __shfl_xor(m, off));
    float s = 0.f;
    #pragma unroll
    for (int k = 0; k < 8; ++k) {
      float e = expf(f[k] - m);
      f[k] = e;
      s += e;
    }
    #pragma unroll
    for (int off = 32; off > 0; off >>= 1)
      s += __shfl_xor(s, off);
    float r = 1.f / s;
    int pos = wave*6 + it;
    #pragma unroll
    for (int k = 0; k < 4; ++k) {
      if (k == 3 && !has4) break;
      int l2 = lane + 64*k;                  // pair index; l = 2*l2
      int lh = l2 / 10, lw = 2*l2 - 20*lh;
      union { bf16_t h[2]; unsigned int u; } pk;
      pk.h[0] = __float2bfloat16(f[2*k]   * r);
      pk.h[1] = __float2bfloat16(f[2*k+1] * r);
      *(unsigned int*)&ysp[pos*576 + (lh+2)*24 + (lw+2)] = pk.u;
    }
  }
  __syncthreads();

  int row = t >> 5;                 // 0..7
  int klane = t & 31;
  int h0r = row >> 2, w0r = row & 3;
  int m = (h0base + h0r)*NW + (w0base + w0r);
  int pblk = m / 80, pf = (m % 80) >> 4, mrow = m & 15;
  size_t rowbase = ((size_t)(b*45 + pblk)*16);
  const unsigned short* basep = ysp + (h0r*6 + w0r)*576;
  for (int kk = 0; kk < 16; ++kk) {
    int k = kk*32 + klane;
    float acc = 0.f;
    if (k < 484) {
      int u = k / 22, v = k - 22*u;
      const unsigned short* q = basep + u*24 + v;
      #pragma unroll
      for (int dh = 0; dh < 3; ++dh) {
        #pragma unroll
        for (int dw = 0; dw < 3; ++dw) {
          unsigned short rbits = q[dh*3480 + dw*577];
          acc += __uint_as_float(((unsigned int)rbits) << 16);
        }
      }
    }
    size_t idx = (((rowbase + (k>>5))*5 + pf)*64 + ((k>>3)&3)*16 + mrow)*8 + (k&7);
    Ap[idx] = __float2bfloat16(acc);
  }
}

// out GEMM: out[(c,rr,s)][(h0,w0)] = (1/6) sum_k Eb[n][k] * A'[m][k]
__global__ __launch_bounds__(64) void k_tgemm(
    const bf16x8* __restrict__ Eb, const bf16x8* __restrict__ Ap,
    float* __restrict__ out) {
  int L = threadIdx.x;
  int pb = blockIdx.x, rb = blockIdx.y, b = blockIdx.z;
  const bf16x8* pa = Eb + ((size_t)(b*12 + rb)*16)*3*64 + L;
  const bf16x8* pp = Ap + ((size_t)(b*45 + pb)*16)*5*64 + L;
  f32x4 acc[3][5];
  #pragma unroll
  for (int i = 0; i < 3; ++i)
    #pragma unroll
    for (int j = 0; j < 5; ++j)
      acc[i][j] = {0.f, 0.f, 0.f, 0.f};
  bf16x8 af[3], bf[5], afn[3], bfn[5];
  #pragma unroll
  for (int i = 0; i < 3; ++i) af[i] = pa[i*64];
  #pragma unroll
  for (int j = 0; j < 5; ++j) bf[j] = pp[j*64];
  for (int ks = 0; ks < 16; ++ks) {
    if (ks < 15) {
      const bf16x8* na = pa + (ks+1)*192;
      const bf16x8* nb = pp + (ks+1)*320;
      #pragma unroll
      for (int i = 0; i < 3; ++i) afn[i] = na[i*64];
      #pragma unroll
      for (int j = 0; j < 5; ++j) bfn[j] = nb[j*64];
    }
    #pragma unroll
    for (int i = 0; i < 3; ++i)
      #pragma unroll
      for (int j = 0; j < 5; ++j)
        acc[i][j] = __builtin_amdgcn_mfma_f32_16x16x32_bf16(af[i], bf[j], acc[i][j], 0, 0, 0);
    #pragma unroll
    for (int i = 0; i < 3; ++i) af[i] = afn[i];
    #pragma unroll
    for (int j = 0; j < 5; ++j) bf[j] = bfn[j];
  }
  int quad = L >> 4, col = L & 15;
  const float sc = 1.f/6.f;
  #pragma unroll
  for (int pf = 0; pf < 5; ++pf) {
    int m = pb*80 + pf*16 + col;
    int h0 = m / 60, w0 = m % 60;
    int posoff = b*(NC*OHW*OHW) + h0*540 + w0*3;
    #pragma unroll
    for (int rf = 0; rf < 3; ++rf) {
      #pragma unroll
      for (int r = 0; r < 4; ++r) {
        int n = rb*48 + rf*16 + quad*4 + r;
        int c = n / 9, n9 = n % 9;
        int rr = n9 / 3, s = n9 % 3;
        out[posoff + c*32400 + rr*180 + s] = acc[rf][pf][r] * sc;
      }
    }
  }
}

extern "C" void kernel_launch(void* const* d_in, const int* in_sizes, int n_in,
                              void* d_out, int out_size, void* d_ws, size_t ws_size,
                              hipStream_t stream) {
  (void)in_sizes; (void)n_in; (void)out_size; (void)ws_size;
  const float* x   = (const float*)d_in[0];
  const float* Wa  = (const float*)d_in[1];
  const float* ba  = (const float*)d_in[2];
  const float* aa  = (const float*)d_in[3];
  const float* Wm1 = (const float*)d_in[4];
  const float* bm1 = (const float*)d_in[5];
  const float* am1 = (const float*)d_in[6];
  const float* Wm2 = (const float*)d_in[7];
  const float* bm2 = (const float*)d_in[8];
  const float* am2 = (const float*)d_in[9];
  float* out = (float*)d_out;

  float* E_t  = (float*)d_ws;
  float* xp   = E_t + SZ_E;
  float* refp = xp + SZ_XP;
  float* invn = refp + SZ_RP;
  float* y_t  = invn + SZ_IN;                            // bf16 logits live here
  bf16_t* y_bl = (bf16_t*)y_t;
  bf16_t* ApSwz = (bf16_t*)(y_t + SZ_Y);                 // 7,372,800 bf16
  bf16_t* EbSwz = ApSwz + (size_t)NB*45*16*5*64*8;       // 1,179,648 bf16
  bf16_t* XpSwz = EbSwz + (size_t)NB*12*16*3*64*8;       // 4,147,200 bf16
  bf16_t* RfSwz = XpSwz + (size_t)NB*225*9*64*8;         //   460,800 bf16

  hipMemsetAsync(d_ws, 0, (size_t)(SZ_E + SZ_XP + SZ_RP)*sizeof(float), stream);

  k_conv<<<5600, 256, 0, stream>>>(x, Wa, ba, aa, Wm1, bm1, am1, Wm2, bm2, am2,
                                   E_t, xp, refp);
  k_invn<<<NB*NL, 64, 0, stream>>>(refp, invn);
  k_swz<<<4554, 256, 0, stream>>>(xp, refp, invn, E_t, XpSwz, RfSwz, EbSwz);
  k_cgemm<<<dim3(5, 75, NB), 64, 0, stream>>>((const bf16x8*)XpSwz, (const bf16x8*)RfSwz, y_bl);
  k_saprime<<<dim3(15, 30, NB), 256, 0, stream>>>((const unsigned int*)y_bl, ApSwz);
  k_tgemm<<<dim3(45, 12, NB), 64, 0, stream>>>((const bf16x8*)EbSwz, (const bf16x8*)ApSwz, out);
}

// Round 9
// 189.810 us; speedup vs baseline: 1.2561x; 1.0621x over previous
//
#include <hip/hip_runtime.h>
#include <hip/hip_bf16.h>

typedef __hip_bfloat16 bf16_t;
using f32x4  = __attribute__((ext_vector_type(4))) float;
using bf16x8 = __attribute__((ext_vector_type(8))) short;

#define NB 4
#define NC 64
#define NC2 32
#define NH 60
#define NW 60
#define NPIX (NH*NW)         // 3600
#define HP 66                // embed padded (pad 3)
#define MP 62                // match padded (pad 1)
#define HR 20
#define RP 22                // ref padded (pad 1)
#define NL 400
#define OHW 180
#define KPAD 512

// workspace layout (floats)
#define SZ_E   (NB*HP*HP*NC)        // 1,115,136  E_t [b][row][col][c]
#define SZ_XP  (NB*NC2*MP*MP)       // 492,032    [b][c][62][62]
#define SZ_RP  (NB*NC2*RP*RP)       // 61,952     [b][c][22][22]
#define SZ_IN  (NB*NL)              // 1,600      (kept for layout stability; unused)
#define SZ_Y   (NB*NPIX*NL)         // region holds bf16 logits
// then bf16: ApSwz 7,372,800 ; EbSwz 1,179,648 ; XpSwz 4,147,200 ; RfSwz 460,800

// merged conv1x1+prelu: [0,3600) embed ; [3600,5400) match ; [5400,5600) ref
__global__ __launch_bounds__(256) void k_conv(
    const float* __restrict__ x,
    const float* __restrict__ Wa,  const float* __restrict__ ba,  const float* __restrict__ aa,
    const float* __restrict__ Wm1, const float* __restrict__ bm1, const float* __restrict__ am1,
    const float* __restrict__ Wm2, const float* __restrict__ bm2, const float* __restrict__ am2,
    float* __restrict__ E_t, float* __restrict__ xp, float* __restrict__ refp) {
  int bid = blockIdx.x;
  int t = threadIdx.x;
  if (bid < 3600) {
    __shared__ float Ws[64*64];
    __shared__ float bs[64];
    __shared__ float al;
    int b = bid / 900, pblk = bid % 900;
    for (int i = t; i < 64*64; i += 256) {
      int co = i >> 6, c = i & 63;
      Ws[c*64 + co] = Wa[i];
    }
    if (t < 64) bs[t] = ba[t];
    if (t == 0) al = aa[0];
    __syncthreads();
    int lane = t & 63, wid = t >> 6;
    int pix = pblk*4 + wid;
    int ph = pix / NW, pw = pix % NW;
    const float* xb = x + b*NC*NPIX + pix;
    float acc = bs[lane];
    #pragma unroll 8
    for (int c = 0; c < 64; ++c)
      acc = fmaf(xb[c*NPIX], Ws[c*64 + lane], acc);
    acc = acc >= 0.f ? acc : al*acc;
    E_t[((b*HP + ph+3)*HP + (pw+3))*NC + lane] = acc;
  } else if (bid < 5400) {
    int idx = (bid - 3600)*256 + t;
    int pix = idx % NPIX; int tmp = idx / NPIX;
    int co = tmp % NC2; int b = tmp / NC2;
    float alpha = am1[0];
    const float* xb = x + b*NC*NPIX + pix;
    const float* wr = Wm1 + co*64;
    float acc = bm1[co];
    #pragma unroll 8
    for (int c = 0; c < 64; ++c)
      acc = fmaf(xb[c*NPIX], wr[c], acc);
    acc = acc >= 0.f ? acc : alpha*acc;
    int ph = pix / NW, pw = pix % NW;
    xp[((b*NC2 + co)*MP + ph+1)*MP + (pw+1)] = acc;
  } else {
    int idx = (bid - 5400)*256 + t;
    int pos = idx % (HR*HR); int tmp = idx / (HR*HR);
    int co = tmp % NC2; int b = tmp / NC2;
    int hr = pos / HR, wr_ = pos % HR;
    float alpha = am2[0];
    const float* xb = x + b*NC*NPIX + (3*hr+1)*NW + (3*wr_+1);
    const float* wrow = Wm2 + co*64;
    float acc = bm2[co];
    #pragma unroll 8
    for (int c = 0; c < 64; ++c)
      acc = fmaf(xb[c*NPIX], wrow[c], acc);
    acc = acc >= 0.f ? acc : alpha*acc;
    refp[((b*NC2 + co)*RP + hr+1)*RP + (wr_+1)] = acc;
  }
}

// merged swizzles: [0,2025) xp-im2col ; [2025,2125) ref patches (norm fused) ;
//                  [2125,4429) Eb
__global__ __launch_bounds__(256) void k_swz(
    const float* __restrict__ xp, const float* __restrict__ refp,
    const float* __restrict__ E_t,
    bf16_t* __restrict__ Xp, bf16_t* __restrict__ Rf, bf16_t* __restrict__ Eb) {
  __shared__ float scl[16];
  int bid = blockIdx.x;
  int t = threadIdx.x;
  if (bid < 2025) {
    int tid = bid*256 + t;             // 518,400 total
    int slot = tid & 63; int rest = tid >> 6;
    int ks = rest % 9; int rest2 = rest / 9;
    int mblk = rest2 % 225; int b = rest2 / 225;
    int m = mblk*16 + (slot & 15);
    int h = m / NW, w = m % NW;
    int k0 = ks*32 + (slot >> 4)*8;
    const float* xb = xp + (size_t)b*NC2*MP*MP;
    union { bf16_t a[8]; bf16x8 v; } u;
    #pragma unroll
    for (int j = 0; j < 8; ++j) {
      int k = k0 + j;
      int c = k / 9, r = k % 9;
      int i = r / 3, j2 = r % 3;
      u.a[j] = __float2bfloat16(xb[(c*MP + h + i)*MP + w + j2]);
    }
    *(bf16x8*)(Xp + (size_t)tid*8) = u.v;
  } else if (bid < 2125) {
    // one block per (b, nblk of 16 l's): compute inv-norms + write Rf swizzled
    int r2 = bid - 2025;               // 100 blocks
    int nblk = r2 % 25, b = r2 / 25;
    int ll = t >> 4, sub = t & 15;     // 16 l's x 16 threads
    int l = nblk*16 + ll;
    int lh = l / HR, lw = l % HR;
    const float* rb = refp + (size_t)b*NC2*RP*RP;
    float ss = 0.f;
    #pragma unroll
    for (int e0 = 0; e0 < 18; ++e0) {
      int e = sub*18 + e0;             // 288 elems per patch
      int c = e / 9, r = e % 9;
      int i = r / 3, j = r % 3;
      float v = rb[(c*RP + lh + i)*RP + lw + j];
      ss = fmaf(v, v, ss);
    }
    #pragma unroll
    for (int off = 1; off < 16; off <<= 1)
      ss += __shfl_xor(ss, off);
    if (sub == 0) scl[ll] = 10.f / fmaxf(sqrtf(ss), 1e-4f);
    __syncthreads();
    for (int sidx = t; sidx < 576; sidx += 256) {   // 9 ks x 64 slots
      int ks = sidx >> 6, slot = sidx & 63;
      int l2 = nblk*16 + (slot & 15);
      int lh2 = l2 / HR, lw2 = l2 % HR;
      float sc = scl[slot & 15];
      int k0 = ks*32 + (slot >> 4)*8;
      union { bf16_t a[8]; bf16x8 v; } u;
      #pragma unroll
      for (int j = 0; j < 8; ++j) {
        int k = k0 + j;
        int c = k / 9, r = k % 9;
        int i = r / 3, j2 = r % 3;
        u.a[j] = __float2bfloat16(rb[(c*RP + lh2 + i)*RP + lw2 + j2] * sc);
      }
      *(bf16x8*)(Rf + ((size_t)(b*25 + nblk)*576 + sidx)*8) = u.v;
    }
  } else {
    int r2 = bid - 2125;               // 2304 blocks
    int n = r2 % 576, b = r2 / 576;
    int c = n / 9, n9 = n % 9, rr = n9 / 3, s = n9 % 3;
    size_t nbase = ((size_t)(b*12 + n/48)*16);
    for (int k = t; k < KPAD; k += 256) {
      float v = 0.f;
      if (k < 484) {
        int u = k / 22, vv = k % 22;
        v = E_t[((size_t)((b*HP + 3*u + rr)*HP + 3*vv + s))*NC + c];
      }
      size_t idx = (((nbase + (k>>5))*3 + (n%48)/16)*64 + ((k>>3)&3)*16 + (n&15))*8 + (k&7);
      Eb[idx] = __float2bfloat16(v);
    }
  }
}

// correlation GEMM: bf16 logits y_bl[b][m][l] = bf16( sum_k Xp[m][k]*Rf[l][k] )
__global__ __launch_bounds__(64) void k_cgemm(
    const bf16x8* __restrict__ Xp, const bf16x8* __restrict__ Rf,
    bf16_t* __restrict__ y_bl) {
  int L = threadIdx.x;
  int nt = blockIdx.x, mt = blockIdx.y, b = blockIdx.z;
  const bf16x8* pa = Xp + ((size_t)(b*225 + mt*3)*9)*64 + L;
  const bf16x8* pb = Rf + ((size_t)(b*25 + nt*5)*9)*64 + L;
  f32x4 acc[3][5];
  #pragma unroll
  for (int i = 0; i < 3; ++i)
    #pragma unroll
    for (int j = 0; j < 5; ++j)
      acc[i][j] = {0.f, 0.f, 0.f, 0.f};
  bf16x8 af[3], bf[5], afn[3], bfn[5];
  #pragma unroll
  for (int i = 0; i < 3; ++i) af[i] = pa[i*576];
  #pragma unroll
  for (int j = 0; j < 5; ++j) bf[j] = pb[j*576];
  for (int ks = 0; ks < 9; ++ks) {
    if (ks < 8) {
      #pragma unroll
      for (int i = 0; i < 3; ++i) afn[i] = pa[i*576 + (ks+1)*64];
      #pragma unroll
      for (int j = 0; j < 5; ++j) bfn[j] = pb[j*576 + (ks+1)*64];
    }
    #pragma unroll
    for (int i = 0; i < 3; ++i)
      #pragma unroll
      for (int j = 0; j < 5; ++j)
        acc[i][j] = __builtin_amdgcn_mfma_f32_16x16x32_bf16(af[i], bf[j], acc[i][j], 0, 0, 0);
    #pragma unroll
    for (int i = 0; i < 3; ++i) af[i] = afn[i];
    #pragma unroll
    for (int j = 0; j < 5; ++j) bf[j] = bfn[j];
  }
  int quad = L >> 4, col = L & 15;
  #pragma unroll
  for (int mf = 0; mf < 3; ++mf) {
    #pragma unroll
    for (int r = 0; r < 4; ++r) {
      int m = mt*48 + mf*16 + quad*4 + r;
      bf16_t* row = y_bl + ((size_t)(b*NPIX + m))*NL + nt*80 + col;
      #pragma unroll
      for (int nf = 0; nf < 5; ++nf)
        row[nf*16] = __float2bfloat16(acc[mf][nf][r]);
    }
  }
}

__device__ __forceinline__ float lo_bf(unsigned int u) {
  return __uint_as_float(u << 16);
}
__device__ __forceinline__ float hi_bf(unsigned int u) {
  return __uint_as_float(u & 0xffff0000u);
}

// fused softmax + A': block = 4x4 output positions, 6x6 halo, 512 threads.
// Phase 1: waves softmax halo positions (4-5 each) from bf16 logits,
//          write bf16 probs into zero-padded LDS window [36][24x24].
// Phase 2: A'[m][k=(u,v)] = 9-point LDS sum, swizzled bf16 store.
__global__ __launch_bounds__(512) void k_saprime(
    const unsigned int* __restrict__ y_b32, bf16_t* __restrict__ Ap) {
  __shared__ uint4 raw[2592];                 // 41472 B: 36 slots x 576 u16
  unsigned short* ysp = (unsigned short*)raw;
  int t = threadIdx.x;
  int b = blockIdx.z;
  int h0base = blockIdx.y*4, w0base = blockIdx.x*4;   // grid (15,15,NB)
  for (int i = t; i < 2592; i += 512) raw[i] = uint4{0,0,0,0};
  __syncthreads();

  int wave = t >> 6, lane = t & 63;
  bool has4 = lane < 8;
  for (int pos = wave; pos < 36; pos += 8) {
    int i = pos / 6, jj = pos % 6;
    int hh = h0base - 1 + i, ww = w0base - 1 + jj;
    if (!((unsigned)hh < NH && (unsigned)ww < NW)) continue;
    const unsigned int* src = y_b32 + ((size_t)(b*NPIX + hh*NW + ww))*200;
    unsigned int v0 = src[lane];
    unsigned int v1 = src[lane+64];
    unsigned int v2 = src[lane+128];
    unsigned int v3 = has4 ? src[lane+192] : 0u;
    float f[8];
    f[0] = lo_bf(v0); f[1] = hi_bf(v0);
    f[2] = lo_bf(v1); f[3] = hi_bf(v1);
    f[4] = lo_bf(v2); f[5] = hi_bf(v2);
    f[6] = has4 ? lo_bf(v3) : -1e30f;
    f[7] = has4 ? hi_bf(v3) : -1e30f;
    float m = -1e30f;
    #pragma unroll
    for (int k = 0; k < 8; ++k) m = fmaxf(m, f[k]);
    #pragma unroll
    for (int off = 32; off > 0; off >>= 1)
      m = fmaxf(m, __shfl_xor(m, off));
    float s = 0.f;
    #pragma unroll
    for (int k = 0; k < 8; ++k) {
      float e = __expf(f[k] - m);
      f[k] = e;
      s += e;
    }
    #pragma unroll
    for (int off = 32; off > 0; off >>= 1)
      s += __shfl_xor(s, off);
    float r = 1.f / s;
    #pragma unroll
    for (int k = 0; k < 4; ++k) {
      if (k == 3 && !has4) break;
      int l2 = lane + 64*k;                  // pair index; l = 2*l2
      int lh = l2 / 10, lw = 2*l2 - 20*lh;
      union { bf16_t h[2]; unsigned int u; } pk;
      pk.h[0] = __float2bfloat16(f[2*k]   * r);
      pk.h[1] = __float2bfloat16(f[2*k+1] * r);
      *(unsigned int*)&ysp[pos*576 + (lh+2)*24 + (lw+2)] = pk.u;
    }
  }
  __syncthreads();

  int row = t >> 5;                 // 0..15
  int klane = t & 31;
  int h0r = row >> 2, w0r = row & 3;
  int m = (h0base + h0r)*NW + (w0base + w0r);
  int pblk = m / 80, pf = (m % 80) >> 4, mrow = m & 15;
  size_t rowbase = ((size_t)(b*45 + pblk)*16);
  const unsigned short* basep = ysp + (h0r*6 + w0r)*576;
  for (int kk = 0; kk < 16; ++kk) {
    int k = kk*32 + klane;
    float acc = 0.f;
    if (k < 484) {
      int u = k / 22, v = k - 22*u;
      const unsigned short* q = basep + u*24 + v;
      #pragma unroll
      for (int dh = 0; dh < 3; ++dh) {
        #pragma unroll
        for (int dw = 0; dw < 3; ++dw) {
          unsigned short rbits = q[dh*3480 + dw*577];
          acc += __uint_as_float(((unsigned int)rbits) << 16);
        }
      }
    }
    size_t idx = (((rowbase + (k>>5))*5 + pf)*64 + ((k>>3)&3)*16 + mrow)*8 + (k&7);
    Ap[idx] = __float2bfloat16(acc);
  }
}

// out GEMM: out[(c,rr,s)][(h0,w0)] = (1/6) sum_k Eb[n][k] * A'[m][k]
__global__ __launch_bounds__(64) void k_tgemm(
    const bf16x8* __restrict__ Eb, const bf16x8* __restrict__ Ap,
    float* __restrict__ out) {
  int L = threadIdx.x;
  int pb = blockIdx.x, rb = blockIdx.y, b = blockIdx.z;
  const bf16x8* pa = Eb + ((size_t)(b*12 + rb)*16)*3*64 + L;
  const bf16x8* pp = Ap + ((size_t)(b*45 + pb)*16)*5*64 + L;
  f32x4 acc[3][5];
  #pragma unroll
  for (int i = 0; i < 3; ++i)
    #pragma unroll
    for (int j = 0; j < 5; ++j)
      acc[i][j] = {0.f, 0.f, 0.f, 0.f};
  bf16x8 af[3], bf[5], afn[3], bfn[5];
  #pragma unroll
  for (int i = 0; i < 3; ++i) af[i] = pa[i*64];
  #pragma unroll
  for (int j = 0; j < 5; ++j) bf[j] = pp[j*64];
  for (int ks = 0; ks < 16; ++ks) {
    if (ks < 15) {
      const bf16x8* na = pa + (ks+1)*192;
      const bf16x8* nb = pp + (ks+1)*320;
      #pragma unroll
      for (int i = 0; i < 3; ++i) afn[i] = na[i*64];
      #pragma unroll
      for (int j = 0; j < 5; ++j) bfn[j] = nb[j*64];
    }
    #pragma unroll
    for (int i = 0; i < 3; ++i)
      #pragma unroll
      for (int j = 0; j < 5; ++j)
        acc[i][j] = __builtin_amdgcn_mfma_f32_16x16x32_bf16(af[i], bf[j], acc[i][j], 0, 0, 0);
    #pragma unroll
    for (int i = 0; i < 3; ++i) af[i] = afn[i];
    #pragma unroll
    for (int j = 0; j < 5; ++j) bf[j] = bfn[j];
  }
  int quad = L >> 4, col = L & 15;
  const float sc = 1.f/6.f;
  #pragma unroll
  for (int pf = 0; pf < 5; ++pf) {
    int m = pb*80 + pf*16 + col;
    int h0 = m / 60, w0 = m % 60;
    int posoff = b*(NC*OHW*OHW) + h0*540 + w0*3;
    #pragma unroll
    for (int rf = 0; rf < 3; ++rf) {
      #pragma unroll
      for (int r = 0; r < 4; ++r) {
        int n = rb*48 + rf*16 + quad*4 + r;
        int c = n / 9, n9 = n % 9;
        int rr = n9 / 3, s = n9 % 3;
        out[posoff + c*32400 + rr*180 + s] = acc[rf][pf][r] * sc;
      }
    }
  }
}

extern "C" void kernel_launch(void* const* d_in, const int* in_sizes, int n_in,
                              void* d_out, int out_size, void* d_ws, size_t ws_size,
                              hipStream_t stream) {
  (void)in_sizes; (void)n_in; (void)out_size; (void)ws_size;
  const float* x   = (const float*)d_in[0];
  const float* Wa  = (const float*)d_in[1];
  const float* ba  = (const float*)d_in[2];
  const float* aa  = (const float*)d_in[3];
  const float* Wm1 = (const float*)d_in[4];
  const float* bm1 = (const float*)d_in[5];
  const float* am1 = (const float*)d_in[6];
  const float* Wm2 = (const float*)d_in[7];
  const float* bm2 = (const float*)d_in[8];
  const float* am2 = (const float*)d_in[9];
  float* out = (float*)d_out;

  float* E_t  = (float*)d_ws;
  float* xp   = E_t + SZ_E;
  float* refp = xp + SZ_XP;
  float* y_t  = refp + SZ_RP + SZ_IN;                    // bf16 logits live here
  bf16_t* y_bl = (bf16_t*)y_t;
  bf16_t* ApSwz = (bf16_t*)(y_t + SZ_Y);                 // 7,372,800 bf16
  bf16_t* EbSwz = ApSwz + (size_t)NB*45*16*5*64*8;       // 1,179,648 bf16
  bf16_t* XpSwz = EbSwz + (size_t)NB*12*16*3*64*8;       // 4,147,200 bf16
  bf16_t* RfSwz = XpSwz + (size_t)NB*225*9*64*8;         //   460,800 bf16

  hipMemsetAsync(d_ws, 0, (size_t)(SZ_E + SZ_XP + SZ_RP)*sizeof(float), stream);

  k_conv<<<5600, 256, 0, stream>>>(x, Wa, ba, aa, Wm1, bm1, am1, Wm2, bm2, am2,
                                   E_t, xp, refp);
  k_swz<<<4429, 256, 0, stream>>>(xp, refp, E_t, XpSwz, RfSwz, EbSwz);
  k_cgemm<<<dim3(5, 75, NB), 64, 0, stream>>>((const bf16x8*)XpSwz, (const bf16x8*)RfSwz, y_bl);
  k_saprime<<<dim3(15, 15, NB), 512, 0, stream>>>((const unsigned int*)y_bl, ApSwz);
  k_tgemm<<<dim3(45, 12, NB), 64, 0, stream>>>((const bf16x8*)EbSwz, (const bf16x8*)ApSwz, out);
}

// Round 10
// 174.121 us; speedup vs baseline: 1.3693x; 1.0901x over previous
//
#include <hip/hip_runtime.h>
#include <hip/hip_bf16.h>

typedef __hip_bfloat16 bf16_t;
using f32x4  = __attribute__((ext_vector_type(4))) float;
using bf16x8 = __attribute__((ext_vector_type(8))) short;

#define NB 4
#define NC 64
#define NC2 32
#define NH 60
#define NW 60
#define NPIX (NH*NW)         // 3600
#define HP 66                // embed padded (pad 3)
#define MP 62                // match padded (pad 1)
#define HR 20
#define RP 22                // ref padded (pad 1)
#define NL 400
#define OHW 180
#define KPAD 512

// workspace layout (floats)
#define SZ_E   (NB*HP*HP*NC)        // 1,115,136  E_t [b][row][col][c]
#define SZ_XP  (NB*NC2*MP*MP)       // 492,032    [b][c][62][62]
#define SZ_RP  (NB*NC2*RP*RP)       // 61,952     [b][c][22][22]
#define SZ_IN  (NB*NL)              // 1,600      (kept for layout stability; unused)
#define SZ_Y   (NB*NPIX*NL)         // region holds bf16 logits
// then bf16: ApSwz 7,372,800 ; EbSwz 1,179,648 ; XpSwz 4,147,200 ; RfSwz 460,800

// merged conv1x1+prelu: [0,300) embed (48 pix/block) ; [300,2100) match ; [2100,2300) ref
__global__ __launch_bounds__(256) void k_conv(
    const float* __restrict__ x,
    const float* __restrict__ Wa,  const float* __restrict__ ba,  const float* __restrict__ aa,
    const float* __restrict__ Wm1, const float* __restrict__ bm1, const float* __restrict__ am1,
    const float* __restrict__ Wm2, const float* __restrict__ bm2, const float* __restrict__ am2,
    float* __restrict__ E_t, float* __restrict__ xp, float* __restrict__ refp) {
  int bid = blockIdx.x;
  int t = threadIdx.x;
  if (bid < 300) {
    __shared__ float Ws[64*64];
    __shared__ float bs[64];
    __shared__ float al;
    int b = bid / 75, pblk = bid % 75;       // 48 pixels per block
    for (int i = t; i < 64*64; i += 256) {
      int co = i >> 6, c = i & 63;
      Ws[c*64 + co] = Wa[i];
    }
    if (t < 64) bs[t] = ba[t];
    if (t == 0) al = aa[0];
    __syncthreads();
    int lane = t & 63, wid = t >> 6;
    int pix0 = pblk*48 + wid*12;             // 12 consecutive pixels per wave
    const float* xb = x + b*NC*NPIX + pix0;  // wave-uniform base
    float acc[12];
    #pragma unroll
    for (int p = 0; p < 12; ++p) acc[p] = bs[lane];
    for (int c = 0; c < 64; ++c) {
      float wv = Ws[c*64 + lane];
      const float* xc = xb + c*NPIX;
      #pragma unroll
      for (int p = 0; p < 12; ++p)
        acc[p] = fmaf(xc[p], wv, acc[p]);
    }
    #pragma unroll
    for (int p = 0; p < 12; ++p) {
      float v = acc[p];
      v = v >= 0.f ? v : al*v;
      int pix = pix0 + p;
      int ph = pix / NW, pw = pix % NW;
      E_t[((b*HP + ph+3)*HP + (pw+3))*NC + lane] = v;
    }
  } else if (bid < 2100) {
    int idx = (bid - 300)*256 + t;
    int pix = idx % NPIX; int tmp = idx / NPIX;
    int co = tmp % NC2; int b = tmp / NC2;
    float alpha = am1[0];
    const float* xb = x + b*NC*NPIX + pix;
    const float* wr = Wm1 + co*64;
    float acc = bm1[co];
    #pragma unroll 8
    for (int c = 0; c < 64; ++c)
      acc = fmaf(xb[c*NPIX], wr[c], acc);
    acc = acc >= 0.f ? acc : alpha*acc;
    int ph = pix / NW, pw = pix % NW;
    xp[((b*NC2 + co)*MP + ph+1)*MP + (pw+1)] = acc;
  } else {
    int idx = (bid - 2100)*256 + t;
    int pos = idx % (HR*HR); int tmp = idx / (HR*HR);
    int co = tmp % NC2; int b = tmp / NC2;
    int hr = pos / HR, wr_ = pos % HR;
    float alpha = am2[0];
    const float* xb = x + b*NC*NPIX + (3*hr+1)*NW + (3*wr_+1);
    const float* wrow = Wm2 + co*64;
    float acc = bm2[co];
    #pragma unroll 8
    for (int c = 0; c < 64; ++c)
      acc = fmaf(xb[c*NPIX], wrow[c], acc);
    acc = acc >= 0.f ? acc : alpha*acc;
    refp[((b*NC2 + co)*RP + hr+1)*RP + (wr_+1)] = acc;
  }
}

// merged swizzles: [0,2025) xp-im2col ; [2025,2125) ref patches (norm fused) ;
//                  [2125,4429) Eb
__global__ __launch_bounds__(256) void k_swz(
    const float* __restrict__ xp, const float* __restrict__ refp,
    const float* __restrict__ E_t,
    bf16_t* __restrict__ Xp, bf16_t* __restrict__ Rf, bf16_t* __restrict__ Eb) {
  __shared__ float scl[16];
  int bid = blockIdx.x;
  int t = threadIdx.x;
  if (bid < 2025) {
    int tid = bid*256 + t;             // 518,400 total
    int slot = tid & 63; int rest = tid >> 6;
    int ks = rest % 9; int rest2 = rest / 9;
    int mblk = rest2 % 225; int b = rest2 / 225;
    int m = mblk*16 + (slot & 15);
    int h = m / NW, w = m % NW;
    int k0 = ks*32 + (slot >> 4)*8;
    const float* xb = xp + (size_t)b*NC2*MP*MP;
    union { bf16_t a[8]; bf16x8 v; } u;
    #pragma unroll
    for (int j = 0; j < 8; ++j) {
      int k = k0 + j;
      int c = k / 9, r = k % 9;
      int i = r / 3, j2 = r % 3;
      u.a[j] = __float2bfloat16(xb[(c*MP + h + i)*MP + w + j2]);
    }
    *(bf16x8*)(Xp + (size_t)tid*8) = u.v;
  } else if (bid < 2125) {
    // one block per (b, nblk of 16 l's): compute inv-norms + write Rf swizzled
    int r2 = bid - 2025;               // 100 blocks
    int nblk = r2 % 25, b = r2 / 25;
    int ll = t >> 4, sub = t & 15;     // 16 l's x 16 threads
    int l = nblk*16 + ll;
    int lh = l / HR, lw = l % HR;
    const float* rb = refp + (size_t)b*NC2*RP*RP;
    float ss = 0.f;
    #pragma unroll
    for (int e0 = 0; e0 < 18; ++e0) {
      int e = sub*18 + e0;             // 288 elems per patch
      int c = e / 9, r = e % 9;
      int i = r / 3, j = r % 3;
      float v = rb[(c*RP + lh + i)*RP + lw + j];
      ss = fmaf(v, v, ss);
    }
    #pragma unroll
    for (int off = 1; off < 16; off <<= 1)
      ss += __shfl_xor(ss, off);
    if (sub == 0) scl[ll] = 10.f / fmaxf(sqrtf(ss), 1e-4f);
    __syncthreads();
    for (int sidx = t; sidx < 576; sidx += 256) {   // 9 ks x 64 slots
      int ks = sidx >> 6, slot = sidx & 63;
      int l2 = nblk*16 + (slot & 15);
      int lh2 = l2 / HR, lw2 = l2 % HR;
      float sc = scl[slot & 15];
      int k0 = ks*32 + (slot >> 4)*8;
      union { bf16_t a[8]; bf16x8 v; } u;
      #pragma unroll
      for (int j = 0; j < 8; ++j) {
        int k = k0 + j;
        int c = k / 9, r = k % 9;
        int i = r / 3, j2 = r % 3;
        u.a[j] = __float2bfloat16(rb[(c*RP + lh2 + i)*RP + lw2 + j2] * sc);
      }
      *(bf16x8*)(Rf + ((size_t)(b*25 + nblk)*576 + sidx)*8) = u.v;
    }
  } else {
    int r2 = bid - 2125;               // 2304 blocks
    int n = r2 % 576, b = r2 / 576;
    int c = n / 9, n9 = n % 9, rr = n9 / 3, s = n9 % 3;
    size_t nbase = ((size_t)(b*12 + n/48)*16);
    for (int k = t; k < KPAD; k += 256) {
      float v = 0.f;
      if (k < 484) {
        int u = k / 22, vv = k % 22;
        v = E_t[((size_t)((b*HP + 3*u + rr)*HP + 3*vv + s))*NC + c];
      }
      size_t idx = (((nbase + (k>>5))*3 + (n%48)/16)*64 + ((k>>3)&3)*16 + (n&15))*8 + (k&7);
      Eb[idx] = __float2bfloat16(v);
    }
  }
}

// correlation GEMM: bf16 logits y_bl[b][m][l] = bf16( sum_k Xp[m][k]*Rf[l][k] )
__global__ __launch_bounds__(64) void k_cgemm(
    const bf16x8* __restrict__ Xp, const bf16x8* __restrict__ Rf,
    bf16_t* __restrict__ y_bl) {
  int L = threadIdx.x;
  int nt = blockIdx.x, mt = blockIdx.y, b = blockIdx.z;
  const bf16x8* pa = Xp + ((size_t)(b*225 + mt*3)*9)*64 + L;
  const bf16x8* pb = Rf + ((size_t)(b*25 + nt*5)*9)*64 + L;
  f32x4 acc[3][5];
  #pragma unroll
  for (int i = 0; i < 3; ++i)
    #pragma unroll
    for (int j = 0; j < 5; ++j)
      acc[i][j] = {0.f, 0.f, 0.f, 0.f};
  bf16x8 af[3], bf[5], afn[3], bfn[5];
  #pragma unroll
  for (int i = 0; i < 3; ++i) af[i] = pa[i*576];
  #pragma unroll
  for (int j = 0; j < 5; ++j) bf[j] = pb[j*576];
  for (int ks = 0; ks < 9; ++ks) {
    if (ks < 8) {
      #pragma unroll
      for (int i = 0; i < 3; ++i) afn[i] = pa[i*576 + (ks+1)*64];
      #pragma unroll
      for (int j = 0; j < 5; ++j) bfn[j] = pb[j*576 + (ks+1)*64];
    }
    #pragma unroll
    for (int i = 0; i < 3; ++i)
      #pragma unroll
      for (int j = 0; j < 5; ++j)
        acc[i][j] = __builtin_amdgcn_mfma_f32_16x16x32_bf16(af[i], bf[j], acc[i][j], 0, 0, 0);
    #pragma unroll
    for (int i = 0; i < 3; ++i) af[i] = afn[i];
    #pragma unroll
    for (int j = 0; j < 5; ++j) bf[j] = bfn[j];
  }
  int quad = L >> 4, col = L & 15;
  #pragma unroll
  for (int mf = 0; mf < 3; ++mf) {
    #pragma unroll
    for (int r = 0; r < 4; ++r) {
      int m = mt*48 + mf*16 + quad*4 + r;
      bf16_t* row = y_bl + ((size_t)(b*NPIX + m))*NL + nt*80 + col;
      #pragma unroll
      for (int nf = 0; nf < 5; ++nf)
        row[nf*16] = __float2bfloat16(acc[mf][nf][r]);
    }
  }
}

__device__ __forceinline__ float lo_bf(unsigned int u) {
  return __uint_as_float(u << 16);
}
__device__ __forceinline__ float hi_bf(unsigned int u) {
  return __uint_as_float(u & 0xffff0000u);
}

// fused softmax + A': block = 4x4 output positions, 6x6 halo, 512 threads.
// Phase 1: waves softmax halo positions from bf16 logits (uint4 loads, lanes
//          0-49 own 8 logits each), write bf16 probs into padded LDS [36][24x24].
// Phase 2: A'[m][k=(u,v)] = 9-point LDS sum, swizzled bf16 store.
__global__ __launch_bounds__(512) void k_saprime(
    const unsigned int* __restrict__ y_b32, bf16_t* __restrict__ Ap) {
  __shared__ uint4 raw[2592];                 // 41472 B: 36 slots x 576 u16
  unsigned short* ysp = (unsigned short*)raw;
  int t = threadIdx.x;
  int b = blockIdx.z;
  int h0base = blockIdx.y*4, w0base = blockIdx.x*4;   // grid (15,15,NB)
  for (int i = t; i < 2592; i += 512) raw[i] = uint4{0,0,0,0};
  __syncthreads();

  int wave = t >> 6, lane = t & 63;
  bool act = lane < 50;
  for (int pos = wave; pos < 36; pos += 8) {
    int i = pos / 6, jj = pos % 6;
    int hh = h0base - 1 + i, ww = w0base - 1 + jj;
    if (!((unsigned)hh < NH && (unsigned)ww < NW)) continue;
    const uint4* src4 = (const uint4*)(y_b32 + ((size_t)(b*NPIX + hh*NW + ww))*200);
    uint4 v = act ? src4[lane] : uint4{0,0,0,0};
    float f[8];
    if (act) {
      f[0] = lo_bf(v.x); f[1] = hi_bf(v.x);
      f[2] = lo_bf(v.y); f[3] = hi_bf(v.y);
      f[4] = lo_bf(v.z); f[5] = hi_bf(v.z);
      f[6] = lo_bf(v.w); f[7] = hi_bf(v.w);
    } else {
      #pragma unroll
      for (int k = 0; k < 8; ++k) f[k] = -1e30f;
    }
    float m = -1e30f;
    #pragma unroll
    for (int k = 0; k < 8; ++k) m = fmaxf(m, f[k]);
    #pragma unroll
    for (int off = 32; off > 0; off >>= 1)
      m = fmaxf(m, __shfl_xor(m, off));
    float s = 0.f;
    #pragma unroll
    for (int k = 0; k < 8; ++k) {
      float e = __expf(f[k] - m);
      f[k] = e;
      s += e;
    }
    #pragma unroll
    for (int off = 32; off > 0; off >>= 1)
      s += __shfl_xor(s, off);
    float r = 1.f / s;
    if (act) {
      #pragma unroll
      for (int k = 0; k < 4; ++k) {
        int l2 = lane*4 + k;                 // pair index; l = 2*l2
        int lh = l2 / 10, lw = 2*l2 - 20*lh;
        union { bf16_t h[2]; unsigned int u; } pk;
        pk.h[0] = __float2bfloat16(f[2*k]   * r);
        pk.h[1] = __float2bfloat16(f[2*k+1] * r);
        *(unsigned int*)&ysp[pos*576 + (lh+2)*24 + (lw+2)] = pk.u;
      }
    }
  }
  __syncthreads();

  int row = t >> 5;                 // 0..15
  int klane = t & 31;
  int h0r = row >> 2, w0r = row & 3;
  int m = (h0base + h0r)*NW + (w0base + w0r);
  int pblk = m / 80, pf = (m % 80) >> 4, mrow = m & 15;
  size_t rowbase = ((size_t)(b*45 + pblk)*16);
  const unsigned short* basep = ysp + (h0r*6 + w0r)*576;
  for (int kk = 0; kk < 16; ++kk) {
    int k = kk*32 + klane;
    float acc = 0.f;
    if (k < 484) {
      int u = k / 22, v = k - 22*u;
      const unsigned short* q = basep + u*24 + v;
      #pragma unroll
      for (int dh = 0; dh < 3; ++dh) {
        #pragma unroll
        for (int dw = 0; dw < 3; ++dw) {
          unsigned short rbits = q[dh*3480 + dw*577];
          acc += __uint_as_float(((unsigned int)rbits) << 16);
        }
      }
    }
    size_t idx = (((rowbase + (k>>5))*5 + pf)*64 + ((k>>3)&3)*16 + mrow)*8 + (k&7);
    Ap[idx] = __float2bfloat16(acc);
  }
}

// out GEMM: out[(c,rr,s)][(h0,w0)] = (1/6) sum_k Eb[n][k] * A'[m][k]
__global__ __launch_bounds__(64) void k_tgemm(
    const bf16x8* __restrict__ Eb, const bf16x8* __restrict__ Ap,
    float* __restrict__ out) {
  int L = threadIdx.x;
  int pb = blockIdx.x, rb = blockIdx.y, b = blockIdx.z;
  const bf16x8* pa = Eb + ((size_t)(b*12 + rb)*16)*3*64 + L;
  const bf16x8* pp = Ap + ((size_t)(b*45 + pb)*16)*5*64 + L;
  f32x4 acc[3][5];
  #pragma unroll
  for (int i = 0; i < 3; ++i)
    #pragma unroll
    for (int j = 0; j < 5; ++j)
      acc[i][j] = {0.f, 0.f, 0.f, 0.f};
  bf16x8 af[3], bf[5], afn[3], bfn[5];
  #pragma unroll
  for (int i = 0; i < 3; ++i) af[i] = pa[i*64];
  #pragma unroll
  for (int j = 0; j < 5; ++j) bf[j] = pp[j*64];
  for (int ks = 0; ks < 16; ++ks) {
    if (ks < 15) {
      const bf16x8* na = pa + (ks+1)*192;
      const bf16x8* nb = pp + (ks+1)*320;
      #pragma unroll
      for (int i = 0; i < 3; ++i) afn[i] = na[i*64];
      #pragma unroll
      for (int j = 0; j < 5; ++j) bfn[j] = nb[j*64];
    }
    #pragma unroll
    for (int i = 0; i < 3; ++i)
      #pragma unroll
      for (int j = 0; j < 5; ++j)
        acc[i][j] = __builtin_amdgcn_mfma_f32_16x16x32_bf16(af[i], bf[j], acc[i][j], 0, 0, 0);
    #pragma unroll
    for (int i = 0; i < 3; ++i) af[i] = afn[i];
    #pragma unroll
    for (int j = 0; j < 5; ++j) bf[j] = bfn[j];
  }
  int quad = L >> 4, col = L & 15;
  const float sc = 1.f/6.f;
  #pragma unroll
  for (int pf = 0; pf < 5; ++pf) {
    int m = pb*80 + pf*16 + col;
    int h0 = m / 60, w0 = m % 60;
    int posoff = b*(NC*OHW*OHW) + h0*540 + w0*3;
    #pragma unroll
    for (int rf = 0; rf < 3; ++rf) {
      #pragma unroll
      for (int r = 0; r < 4; ++r) {
        int n = rb*48 + rf*16 + quad*4 + r;
        int c = n / 9, n9 = n % 9;
        int rr = n9 / 3, s = n9 % 3;
        out[posoff + c*32400 + rr*180 + s] = acc[rf][pf][r] * sc;
      }
    }
  }
}

extern "C" void kernel_launch(void* const* d_in, const int* in_sizes, int n_in,
                              void* d_out, int out_size, void* d_ws, size_t ws_size,
                              hipStream_t stream) {
  (void)in_sizes; (void)n_in; (void)out_size; (void)ws_size;
  const float* x   = (const float*)d_in[0];
  const float* Wa  = (const float*)d_in[1];
  const float* ba  = (const float*)d_in[2];
  const float* aa  = (const float*)d_in[3];
  const float* Wm1 = (const float*)d_in[4];
  const float* bm1 = (const float*)d_in[5];
  const float* am1 = (const float*)d_in[6];
  const float* Wm2 = (const float*)d_in[7];
  const float* bm2 = (const float*)d_in[8];
  const float* am2 = (const float*)d_in[9];
  float* out = (float*)d_out;

  float* E_t  = (float*)d_ws;
  float* xp   = E_t + SZ_E;
  float* refp = xp + SZ_XP;
  float* y_t  = refp + SZ_RP + SZ_IN;                    // bf16 logits live here
  bf16_t* y_bl = (bf16_t*)y_t;
  bf16_t* ApSwz = (bf16_t*)(y_t + SZ_Y);                 // 7,372,800 bf16
  bf16_t* EbSwz = ApSwz + (size_t)NB*45*16*5*64*8;       // 1,179,648 bf16
  bf16_t* XpSwz = EbSwz + (size_t)NB*12*16*3*64*8;       // 4,147,200 bf16
  bf16_t* RfSwz = XpSwz + (size_t)NB*225*9*64*8;         //   460,800 bf16

  hipMemsetAsync(d_ws, 0, (size_t)(SZ_E + SZ_XP + SZ_RP)*sizeof(float), stream);

  k_conv<<<2300, 256, 0, stream>>>(x, Wa, ba, aa, Wm1, bm1, am1, Wm2, bm2, am2,
                                   E_t, xp, refp);
  k_swz<<<4429, 256, 0, stream>>>(xp, refp, E_t, XpSwz, RfSwz, EbSwz);
  k_cgemm<<<dim3(5, 75, NB), 64, 0, stream>>>((const bf16x8*)XpSwz, (const bf16x8*)RfSwz, y_bl);
  k_saprime<<<dim3(15, 15, NB), 512, 0, stream>>>((const unsigned int*)y_bl, ApSwz);
  k_tgemm<<<dim3(45, 12, NB), 64, 0, stream>>>((const bf16x8*)EbSwz, (const bf16x8*)ApSwz, out);
}

// Round 11
// 173.398 us; speedup vs baseline: 1.3750x; 1.0042x over previous
//
#include <hip/hip_runtime.h>
#include <hip/hip_bf16.h>

typedef __hip_bfloat16 bf16_t;
using f32x4  = __attribute__((ext_vector_type(4))) float;
using bf16x8 = __attribute__((ext_vector_type(8))) short;

#define NB 4
#define NC 64
#define NC2 32
#define NH 60
#define NW 60
#define NPIX (NH*NW)         // 3600
#define HP 66                // embed padded (pad 3)
#define MP 62                // match padded (pad 1)
#define HR 20
#define RP 22                // ref padded (pad 1)
#define NL 400
#define OHW 180
#define KPAD 512

// workspace layout (bytes):
//   E_bt  bf16  2,230,272
//   xpb   bf16    984,064
//   refp  f32     247,808   (memset covers the above three = 3,462,144 B)
//   y_bl  bf16 11,520,000
//   ApSwz bf16 14,745,600
//   EbSwz bf16  2,359,296
//   XpSwz bf16  8,294,400
//   RfSwz bf16    921,600
#define OFF_XPB   2230272
#define OFF_REFP  3214336
#define OFF_YBL   3462144
#define OFF_AP    14982144
#define OFF_EB    29727744
#define OFF_XP    32087040
#define OFF_RF    40381440

// merged conv1x1+prelu: [0,300) embed (48 pix/block, bf16 out) ;
//                       [300,2100) match (bf16 out) ; [2100,2300) ref (fp32 out)
__global__ __launch_bounds__(256) void k_conv(
    const float* __restrict__ x,
    const float* __restrict__ Wa,  const float* __restrict__ ba,  const float* __restrict__ aa,
    const float* __restrict__ Wm1, const float* __restrict__ bm1, const float* __restrict__ am1,
    const float* __restrict__ Wm2, const float* __restrict__ bm2, const float* __restrict__ am2,
    bf16_t* __restrict__ E_bt, bf16_t* __restrict__ xpb, float* __restrict__ refp) {
  int bid = blockIdx.x;
  int t = threadIdx.x;
  if (bid < 300) {
    __shared__ float Ws[64*64];
    __shared__ float bs[64];
    __shared__ float al;
    int b = bid / 75, pblk = bid % 75;       // 48 pixels per block
    for (int i = t; i < 64*64; i += 256) {
      int co = i >> 6, c = i & 63;
      Ws[c*64 + co] = Wa[i];
    }
    if (t < 64) bs[t] = ba[t];
    if (t == 0) al = aa[0];
    __syncthreads();
    int lane = t & 63, wid = t >> 6;
    int pix0 = pblk*48 + wid*12;             // 12 consecutive pixels per wave
    const float* xb = x + b*NC*NPIX + pix0;  // wave-uniform base
    float acc[12];
    #pragma unroll
    for (int p = 0; p < 12; ++p) acc[p] = bs[lane];
    for (int c = 0; c < 64; ++c) {
      float wv = Ws[c*64 + lane];
      const float* xc = xb + c*NPIX;
      #pragma unroll
      for (int p = 0; p < 12; ++p)
        acc[p] = fmaf(xc[p], wv, acc[p]);
    }
    #pragma unroll
    for (int p = 0; p < 12; ++p) {
      float v = acc[p];
      v = v >= 0.f ? v : al*v;
      int pix = pix0 + p;
      int ph = pix / NW, pw = pix % NW;
      E_bt[((b*HP + ph+3)*HP + (pw+3))*NC + lane] = __float2bfloat16(v);
    }
  } else if (bid < 2100) {
    int idx = (bid - 300)*256 + t;
    int pix = idx % NPIX; int tmp = idx / NPIX;
    int co = tmp % NC2; int b = tmp / NC2;
    float alpha = am1[0];
    const float* xb = x + b*NC*NPIX + pix;
    const float* wr = Wm1 + co*64;
    float acc = bm1[co];
    #pragma unroll 8
    for (int c = 0; c < 64; ++c)
      acc = fmaf(xb[c*NPIX], wr[c], acc);
    acc = acc >= 0.f ? acc : alpha*acc;
    int ph = pix / NW, pw = pix % NW;
    xpb[((b*NC2 + co)*MP + ph+1)*MP + (pw+1)] = __float2bfloat16(acc);
  } else {
    int idx = (bid - 2100)*256 + t;
    int pos = idx % (HR*HR); int tmp = idx / (HR*HR);
    int co = tmp % NC2; int b = tmp / NC2;
    int hr = pos / HR, wr_ = pos % HR;
    float alpha = am2[0];
    const float* xb = x + b*NC*NPIX + (3*hr+1)*NW + (3*wr_+1);
    const float* wrow = Wm2 + co*64;
    float acc = bm2[co];
    #pragma unroll 8
    for (int c = 0; c < 64; ++c)
      acc = fmaf(xb[c*NPIX], wrow[c], acc);
    acc = acc >= 0.f ? acc : alpha*acc;
    refp[((b*NC2 + co)*RP + hr+1)*RP + (wr_+1)] = acc;
  }
}

// merged swizzles: [0,2025) xp-im2col (bf16 copy) ;
//                  [2025,2125) ref patches (norm fused, fp32->bf16) ;
//                  [2125,4429) Eb (u16 gather)
__global__ __launch_bounds__(256) void k_swz(
    const bf16_t* __restrict__ xpb, const float* __restrict__ refp,
    const bf16_t* __restrict__ E_bt,
    bf16_t* __restrict__ Xp, bf16_t* __restrict__ Rf, bf16_t* __restrict__ Eb) {
  __shared__ float scl[16];
  int bid = blockIdx.x;
  int t = threadIdx.x;
  if (bid < 2025) {
    int tid = bid*256 + t;             // 518,400 total
    int slot = tid & 63; int rest = tid >> 6;
    int ks = rest % 9; int rest2 = rest / 9;
    int mblk = rest2 % 225; int b = rest2 / 225;
    int m = mblk*16 + (slot & 15);
    int h = m / NW, w = m % NW;
    int k0 = ks*32 + (slot >> 4)*8;
    const bf16_t* xb = xpb + (size_t)b*NC2*MP*MP;
    union { bf16_t a[8]; bf16x8 v; } u;
    #pragma unroll
    for (int j = 0; j < 8; ++j) {
      int k = k0 + j;
      int c = k / 9, r = k % 9;
      int i = r / 3, j2 = r % 3;
      u.a[j] = xb[(c*MP + h + i)*MP + w + j2];
    }
    *(bf16x8*)(Xp + (size_t)tid*8) = u.v;
  } else if (bid < 2125) {
    // one block per (b, nblk of 16 l's): compute inv-norms + write Rf swizzled
    int r2 = bid - 2025;               // 100 blocks
    int nblk = r2 % 25, b = r2 / 25;
    int ll = t >> 4, sub = t & 15;     // 16 l's x 16 threads
    int l = nblk*16 + ll;
    int lh = l / HR, lw = l % HR;
    const float* rb = refp + (size_t)b*NC2*RP*RP;
    float ss = 0.f;
    #pragma unroll
    for (int e0 = 0; e0 < 18; ++e0) {
      int e = sub*18 + e0;             // 288 elems per patch
      int c = e / 9, r = e % 9;
      int i = r / 3, j = r % 3;
      float v = rb[(c*RP + lh + i)*RP + lw + j];
      ss = fmaf(v, v, ss);
    }
    #pragma unroll
    for (int off = 1; off < 16; off <<= 1)
      ss += __shfl_xor(ss, off);
    if (sub == 0) scl[ll] = 10.f / fmaxf(sqrtf(ss), 1e-4f);
    __syncthreads();
    for (int sidx = t; sidx < 576; sidx += 256) {   // 9 ks x 64 slots
      int ks = sidx >> 6, slot = sidx & 63;
      int l2 = nblk*16 + (slot & 15);
      int lh2 = l2 / HR, lw2 = l2 % HR;
      float sc = scl[slot & 15];
      int k0 = ks*32 + (slot >> 4)*8;
      union { bf16_t a[8]; bf16x8 v; } u;
      #pragma unroll
      for (int j = 0; j < 8; ++j) {
        int k = k0 + j;
        int c = k / 9, r = k % 9;
        int i = r / 3, j2 = r % 3;
        u.a[j] = __float2bfloat16(rb[(c*RP + lh2 + i)*RP + lw2 + j2] * sc);
      }
      *(bf16x8*)(Rf + ((size_t)(b*25 + nblk)*576 + sidx)*8) = u.v;
    }
  } else {
    int r2 = bid - 2125;               // 2304 blocks
    int n = r2 % 576, b = r2 / 576;
    int c = n / 9, n9 = n % 9, rr = n9 / 3, s = n9 % 3;
    size_t nbase = ((size_t)(b*12 + n/48)*16);
    const unsigned short* Eu = (const unsigned short*)E_bt;
    unsigned short* Ebu = (unsigned short*)Eb;
    for (int k = t; k < KPAD; k += 256) {
      unsigned short v = 0;
      if (k < 484) {
        int u = k / 22, vv = k % 22;
        v = Eu[((size_t)((b*HP + 3*u + rr)*HP + 3*vv + s))*NC + c];
      }
      size_t idx = (((nbase + (k>>5))*3 + (n%48)/16)*64 + ((k>>3)&3)*16 + (n&15))*8 + (k&7);
      Ebu[idx] = v;
    }
  }
}

// correlation GEMM: bf16 logits y_bl[b][m][l] = bf16( sum_k Xp[m][k]*Rf[l][k] )
__global__ __launch_bounds__(64) void k_cgemm(
    const bf16x8* __restrict__ Xp, const bf16x8* __restrict__ Rf,
    bf16_t* __restrict__ y_bl) {
  int L = threadIdx.x;
  int nt = blockIdx.x, mt = blockIdx.y, b = blockIdx.z;
  const bf16x8* pa = Xp + ((size_t)(b*225 + mt*3)*9)*64 + L;
  const bf16x8* pb = Rf + ((size_t)(b*25 + nt*5)*9)*64 + L;
  f32x4 acc[3][5];
  #pragma unroll
  for (int i = 0; i < 3; ++i)
    #pragma unroll
    for (int j = 0; j < 5; ++j)
      acc[i][j] = {0.f, 0.f, 0.f, 0.f};
  bf16x8 af[3], bf[5], afn[3], bfn[5];
  #pragma unroll
  for (int i = 0; i < 3; ++i) af[i] = pa[i*576];
  #pragma unroll
  for (int j = 0; j < 5; ++j) bf[j] = pb[j*576];
  for (int ks = 0; ks < 9; ++ks) {
    if (ks < 8) {
      #pragma unroll
      for (int i = 0; i < 3; ++i) afn[i] = pa[i*576 + (ks+1)*64];
      #pragma unroll
      for (int j = 0; j < 5; ++j) bfn[j] = pb[j*576 + (ks+1)*64];
    }
    #pragma unroll
    for (int i = 0; i < 3; ++i)
      #pragma unroll
      for (int j = 0; j < 5; ++j)
        acc[i][j] = __builtin_amdgcn_mfma_f32_16x16x32_bf16(af[i], bf[j], acc[i][j], 0, 0, 0);
    #pragma unroll
    for (int i = 0; i < 3; ++i) af[i] = afn[i];
    #pragma unroll
    for (int j = 0; j < 5; ++j) bf[j] = bfn[j];
  }
  int quad = L >> 4, col = L & 15;
  #pragma unroll
  for (int mf = 0; mf < 3; ++mf) {
    #pragma unroll
    for (int r = 0; r < 4; ++r) {
      int m = mt*48 + mf*16 + quad*4 + r;
      bf16_t* row = y_bl + ((size_t)(b*NPIX + m))*NL + nt*80 + col;
      #pragma unroll
      for (int nf = 0; nf < 5; ++nf)
        row[nf*16] = __float2bfloat16(acc[mf][nf][r]);
    }
  }
}

__device__ __forceinline__ float lo_bf(unsigned int u) {
  return __uint_as_float(u << 16);
}
__device__ __forceinline__ float hi_bf(unsigned int u) {
  return __uint_as_float(u & 0xffff0000u);
}
__device__ __forceinline__ float u16_bf(unsigned short u) {
  return __uint_as_float(((unsigned int)u) << 16);
}
__device__ __forceinline__ unsigned short bf_bits(float f) {
  union { bf16_t h; unsigned short u; } c;
  c.h = __float2bfloat16(f);
  return c.u;
}

// fused softmax + A': block = 4x4 output positions, 6x6 halo, 512 threads.
// Phase 1: waves softmax halo positions from bf16 logits (uint4 loads),
//          write bf16 probs into padded LDS [36][24x24].
// Phase 2: A'[m][k] for k-PAIRS (k even): dw=0/2 taps come as aligned u32
//          pairs from LDS; packed u32 store into swizzled Ap.
__global__ __launch_bounds__(512) void k_saprime(
    const unsigned int* __restrict__ y_b32, bf16_t* __restrict__ Ap) {
  __shared__ uint4 raw[2592];                 // 41472 B: 36 slots x 576 u16
  unsigned short* ysp = (unsigned short*)raw;
  int t = threadIdx.x;
  int b = blockIdx.z;
  int h0base = blockIdx.y*4, w0base = blockIdx.x*4;   // grid (15,15,NB)
  for (int i = t; i < 2592; i += 512) raw[i] = uint4{0,0,0,0};
  __syncthreads();

  int wave = t >> 6, lane = t & 63;
  bool act = lane < 50;
  for (int pos = wave; pos < 36; pos += 8) {
    int i = pos / 6, jj = pos % 6;
    int hh = h0base - 1 + i, ww = w0base - 1 + jj;
    if (!((unsigned)hh < NH && (unsigned)ww < NW)) continue;
    const uint4* src4 = (const uint4*)(y_b32 + ((size_t)(b*NPIX + hh*NW + ww))*200);
    uint4 v = act ? src4[lane] : uint4{0,0,0,0};
    float f[8];
    if (act) {
      f[0] = lo_bf(v.x); f[1] = hi_bf(v.x);
      f[2] = lo_bf(v.y); f[3] = hi_bf(v.y);
      f[4] = lo_bf(v.z); f[5] = hi_bf(v.z);
      f[6] = lo_bf(v.w); f[7] = hi_bf(v.w);
    } else {
      #pragma unroll
      for (int k = 0; k < 8; ++k) f[k] = -1e30f;
    }
    float m = -1e30f;
    #pragma unroll
    for (int k = 0; k < 8; ++k) m = fmaxf(m, f[k]);
    #pragma unroll
    for (int off = 32; off > 0; off >>= 1)
      m = fmaxf(m, __shfl_xor(m, off));
    float s = 0.f;
    #pragma unroll
    for (int k = 0; k < 8; ++k) {
      float e = __expf(f[k] - m);
      f[k] = e;
      s += e;
    }
    #pragma unroll
    for (int off = 32; off > 0; off >>= 1)
      s += __shfl_xor(s, off);
    float r = 1.f / s;
    if (act) {
      #pragma unroll
      for (int k = 0; k < 4; ++k) {
        int l2 = lane*4 + k;                 // pair index; l = 2*l2
        int lh = l2 / 10, lw = 2*l2 - 20*lh;
        union { bf16_t h[2]; unsigned int u; } pk;
        pk.h[0] = __float2bfloat16(f[2*k]   * r);
        pk.h[1] = __float2bfloat16(f[2*k+1] * r);
        *(unsigned int*)&ysp[pos*576 + (lh+2)*24 + (lw+2)] = pk.u;
      }
    }
  }
  __syncthreads();

  int row = t >> 5;                 // 0..15
  int klane = t & 31;               // handles pair (k, k+1), k = kk*64 + 2*klane
  int h0r = row >> 2, w0r = row & 3;
  int m = (h0base + h0r)*NW + (w0base + w0r);
  int pblk = m / 80, pf = (m % 80) >> 4, mrow = m & 15;
  size_t rowbase = ((size_t)(b*45 + pblk)*16);
  const unsigned short* basep = ysp + (h0r*6 + w0r)*576;
  unsigned short* Apu = (unsigned short*)Ap;
  for (int kk = 0; kk < 8; ++kk) {
    int k = kk*64 + 2*klane;        // even; v = k%22 even -> no row straddle
    float a0 = 0.f, a1 = 0.f;
    if (k < 484) {
      int u = k / 22, v = k - 22*u;
      const unsigned short* q = basep + u*24 + v;   // even short offset
      #pragma unroll
      for (int dh = 0; dh < 3; ++dh) {
        unsigned int p0 = *(const unsigned int*)(q + dh*3480);        // dw=0
        a0 += lo_bf(p0); a1 += hi_bf(p0);
        a0 += u16_bf(q[dh*3480 + 577]);                               // dw=1
        a1 += u16_bf(q[dh*3480 + 578]);
        unsigned int p2 = *(const unsigned int*)(q + dh*3480 + 1154); // dw=2
        a0 += lo_bf(p2); a1 += hi_bf(p2);
      }
    }
    unsigned int pk = ((unsigned int)bf_bits(a1) << 16) | bf_bits(a0);
    size_t idx = (((rowbase + (k>>5))*5 + pf)*64 + ((k>>3)&3)*16 + mrow)*8 + (k&7);
    *(unsigned int*)&Apu[idx] = pk;   // idx even -> 4B aligned
  }
}

// out GEMM: out[(c,rr,s)][(h0,w0)] = (1/6) sum_k Eb[n][k] * A'[m][k]
__global__ __launch_bounds__(64) void k_tgemm(
    const bf16x8* __restrict__ Eb, const bf16x8* __restrict__ Ap,
    float* __restrict__ out) {
  int L = threadIdx.x;
  int pb = blockIdx.x, rb = blockIdx.y, b = blockIdx.z;
  const bf16x8* pa = Eb + ((size_t)(b*12 + rb)*16)*3*64 + L;
  const bf16x8* pp = Ap + ((size_t)(b*45 + pb)*16)*5*64 + L;
  f32x4 acc[3][5];
  #pragma unroll
  for (int i = 0; i < 3; ++i)
    #pragma unroll
    for (int j = 0; j < 5; ++j)
      acc[i][j] = {0.f, 0.f, 0.f, 0.f};
  bf16x8 af[3], bf[5], afn[3], bfn[5];
  #pragma unroll
  for (int i = 0; i < 3; ++i) af[i] = pa[i*64];
  #pragma unroll
  for (int j = 0; j < 5; ++j) bf[j] = pp[j*64];
  for (int ks = 0; ks < 16; ++ks) {
    if (ks < 15) {
      const bf16x8* na = pa + (ks+1)*192;
      const bf16x8* nb = pp + (ks+1)*320;
      #pragma unroll
      for (int i = 0; i < 3; ++i) afn[i] = na[i*64];
      #pragma unroll
      for (int j = 0; j < 5; ++j) bfn[j] = nb[j*64];
    }
    #pragma unroll
    for (int i = 0; i < 3; ++i)
      #pragma unroll
      for (int j = 0; j < 5; ++j)
        acc[i][j] = __builtin_amdgcn_mfma_f32_16x16x32_bf16(af[i], bf[j], acc[i][j], 0, 0, 0);
    #pragma unroll
    for (int i = 0; i < 3; ++i) af[i] = afn[i];
    #pragma unroll
    for (int j = 0; j < 5; ++j) bf[j] = bfn[j];
  }
  int quad = L >> 4, col = L & 15;
  const float sc = 1.f/6.f;
  #pragma unroll
  for (int pf = 0; pf < 5; ++pf) {
    int m = pb*80 + pf*16 + col;
    int h0 = m / 60, w0 = m % 60;
    int posoff = b*(NC*OHW*OHW) + h0*540 + w0*3;
    #pragma unroll
    for (int rf = 0; rf < 3; ++rf) {
      #pragma unroll
      for (int r = 0; r < 4; ++r) {
        int n = rb*48 + rf*16 + quad*4 + r;
        int c = n / 9, n9 = n % 9;
        int rr = n9 / 3, s = n9 % 3;
        out[posoff + c*32400 + rr*180 + s] = acc[rf][pf][r] * sc;
      }
    }
  }
}

extern "C" void kernel_launch(void* const* d_in, const int* in_sizes, int n_in,
                              void* d_out, int out_size, void* d_ws, size_t ws_size,
                              hipStream_t stream) {
  (void)in_sizes; (void)n_in; (void)out_size; (void)ws_size;
  const float* x   = (const float*)d_in[0];
  const float* Wa  = (const float*)d_in[1];
  const float* ba  = (const float*)d_in[2];
  const float* aa  = (const float*)d_in[3];
  const float* Wm1 = (const float*)d_in[4];
  const float* bm1 = (const float*)d_in[5];
  const float* am1 = (const float*)d_in[6];
  const float* Wm2 = (const float*)d_in[7];
  const float* bm2 = (const float*)d_in[8];
  const float* am2 = (const float*)d_in[9];
  float* out = (float*)d_out;

  char* base = (char*)d_ws;
  bf16_t* E_bt  = (bf16_t*)base;
  bf16_t* xpb   = (bf16_t*)(base + OFF_XPB);
  float*  refp  = (float*)(base + OFF_REFP);
  bf16_t* y_bl  = (bf16_t*)(base + OFF_YBL);
  bf16_t* ApSwz = (bf16_t*)(base + OFF_AP);
  bf16_t* EbSwz = (bf16_t*)(base + OFF_EB);
  bf16_t* XpSwz = (bf16_t*)(base + OFF_XP);
  bf16_t* RfSwz = (bf16_t*)(base + OFF_RF);

  // zero E_bt + xpb + refp (pad rings must read as 0)
  hipMemsetAsync(d_ws, 0, (size_t)OFF_YBL, stream);

  k_conv<<<2300, 256, 0, stream>>>(x, Wa, ba, aa, Wm1, bm1, am1, Wm2, bm2, am2,
                                   E_bt, xpb, refp);
  k_swz<<<4429, 256, 0, stream>>>(xpb, refp, E_bt, XpSwz, RfSwz, EbSwz);
  k_cgemm<<<dim3(5, 75, NB), 64, 0, stream>>>((const bf16x8*)XpSwz, (const bf16x8*)RfSwz, y_bl);
  k_saprime<<<dim3(15, 15, NB), 512, 0, stream>>>((const unsigned int*)y_bl, ApSwz);
  k_tgemm<<<dim3(45, 12, NB), 64, 0, stream>>>((const bf16x8*)EbSwz, (const bf16x8*)ApSwz, out);
}